// Round 2
// baseline (865.793 us; speedup 1.0000x reference)
//
#include <hip/hip_runtime.h>

// ---- problem constants (B,H0,W0,C)=(16,56,56,96), NH=3, WS=7, SS=3, HID=384, NCL=128 ----
#define NB 16
#define NHH 56
#define NWW 56
#define NC 96
#define NL (NHH*NWW)          // 3136
#define NTOK (NB*NL)          // 50176
#define WSZ 7
#define NT 49                 // tokens per window
#define SSH 3
#define NWIN 1024             // 16 * 8 * 8
#define HDIM 32
#define HID_ 384
#define NCL_ 128
#define NLIT 768
#define EPS_ 1e-6f

typedef unsigned short u16;
typedef unsigned int   u32;

__device__ __forceinline__ float us2f(u16 u) {
  union { u32 u; float f; } x; x.u = ((u32)u) << 16; return x.f;
}
__device__ __forceinline__ u16 f2us(float f) {   // RNE float->bf16
  union { float f; u32 u; } x; x.f = f;
  u32 lsb = (x.u >> 16) & 1u;
  return (u16)((x.u + 0x7fffu + lsb) >> 16);
}
__device__ __forceinline__ float wsum(float v) {
  #pragma unroll
  for (int off = 32; off > 0; off >>= 1) v += __shfl_down(v, off, 64);
  return __shfl(v, 0, 64);
}
__device__ __forceinline__ float sigmoidf_(float x) { return 1.f / (1.f + __expf(-x)); }

// ---------------- K0: mask[j][k] = (tm_inc[k][j] > 0) ----------------
__global__ __launch_bounds__(256) void k0_mask(const float* __restrict__ tm_inc,
                                               unsigned char* __restrict__ mask) {
  int idx = blockIdx.x * 256 + threadIdx.x;
  if (idx < NCL_ * NLIT) {
    int k = idx / NLIT, j = idx - k * NLIT;
    mask[(size_t)j * NCL_ + k] = (tm_inc[idx] > 0.f) ? 1 : 0;
  }
}

// ---------------- K1: LN1 + global roll(-3,-3) + window gather ----------------
__global__ __launch_bounds__(256) void k1_ln_gather(const float* __restrict__ x,
                                                    const float* __restrict__ g,
                                                    const float* __restrict__ b,
                                                    float* __restrict__ wy) {
  int lane = threadIdx.x & 63;
  int token = (blockIdx.x << 2) + (threadIdx.x >> 6);
  const float* xp = x + (size_t)token * NC;
  float v0 = xp[lane];
  float v1 = (lane < 32) ? xp[64 + lane] : 0.f;
  float mean = wsum(v0 + v1) * (1.f / 96.f);
  float d0 = v0 - mean;
  float d1 = (lane < 32) ? (v1 - mean) : 0.f;
  float var = wsum(d0 * d0 + d1 * d1) * (1.f / 96.f);
  float rstd = rsqrtf(var + 1e-5f);
  int bb = token / NL, l = token - bb * NL;
  int h = l / NWW, w = l - h * NWW;
  int hp = h - SSH; if (hp < 0) hp += NHH;
  int wp = w - SSH; if (wp < 0) wp += NWW;
  int win = bb * 64 + (hp / WSZ) * 8 + (wp / WSZ);
  int tw = (hp % WSZ) * WSZ + (wp % WSZ);
  float* dst = wy + ((size_t)win * NT + tw) * NC;
  dst[lane] = d0 * rstd * g[lane] + b[lane];
  if (lane < 32) dst[64 + lane] = d1 * rstd * g[64 + lane] + b[64 + lane];
}

// ---------------- K2: per-window QKV + attention + proj + residual scatter ----------------
// LDS floats: sy[52*100] | sq[52*100] | sk[52*100] | sv[52*100] | su[9312]
// su in time-order: qkv_w chunk (96x97) -> scores (147x52) -> proj_w (96x97)
__global__ __launch_bounds__(256) void k2_attn(const float* __restrict__ wy,
                                               const float* __restrict__ qkv_w,
                                               const float* __restrict__ qkv_b,
                                               const float* __restrict__ proj_w,
                                               const float* __restrict__ proj_b,
                                               const float* __restrict__ x,
                                               float* __restrict__ x1) {
  __shared__ float smem[30112];   // 120,448 B
  float* sy = smem;
  float* sq = smem + 5200;
  float* sk = smem + 10400;
  float* sv = smem + 15600;
  float* su = smem + 20800;
  const int tid = threadIdx.x;
  const int win = blockIdx.x;

  // stage window input (rows 49..51 zero-padded)
  for (int idx = tid; idx < 52 * NC; idx += 256) {
    int t = idx / NC, c = idx - t * NC;
    sy[t * 100 + c] = (t < NT) ? wy[((size_t)win * NT + t) * NC + c] : 0.f;
  }

  // QKV gemm in 3 chunks of 96 output cols (q, k, v)
  for (int part = 0; part < 3; ++part) {
    for (int idx = tid; idx < NC * NC; idx += 256) {
      int o = idx / NC, c = idx - o * NC;
      su[o * 97 + c] = qkv_w[(size_t)(part * NC + o) * NC + c];
    }
    __syncthreads();
    float* dst = (part == 0) ? sq : (part == 1) ? sk : sv;
    for (int tile = tid; tile < 312; tile += 256) {   // 13 t-tiles x 24 o-tiles
      int tt = tile / 24, ot = tile - tt * 24;
      int t0 = tt * 4, o0 = ot * 4;
      float acc[4][4] = {};
      for (int c = 0; c < NC; ++c) {
        float a0 = sy[(t0 + 0) * 100 + c], a1 = sy[(t0 + 1) * 100 + c];
        float a2 = sy[(t0 + 2) * 100 + c], a3 = sy[(t0 + 3) * 100 + c];
        #pragma unroll
        for (int j = 0; j < 4; ++j) {
          float wv = su[(o0 + j) * 97 + c];
          acc[0][j] += a0 * wv; acc[1][j] += a1 * wv;
          acc[2][j] += a2 * wv; acc[3][j] += a3 * wv;
        }
      }
      #pragma unroll
      for (int j = 0; j < 4; ++j) {
        float bias = qkv_b[part * NC + o0 + j];
        #pragma unroll
        for (int i = 0; i < 4; ++i)
          dst[(t0 + i) * 100 + o0 + j] = (t0 + i < NT) ? (acc[i][j] + bias) : 0.f;
      }
    }
    __syncthreads();
  }

  // scores S[h][t][s] = (q.k)/sqrt(32)  into su (stride 52)
  float* sc = su;
  for (int tile = tid; tile < 507; tile += 256) {   // 3 heads x 13 x 13
    int hh = tile / 169, rem = tile - hh * 169;
    int rt = rem / 13;
    int t0 = rt * 4, s0 = (rem - rt * 13) * 4;
    const float* qb = sq + hh * HDIM;
    const float* kb = sk + hh * HDIM;
    float acc[4][4] = {};
    for (int d = 0; d < HDIM; ++d) {
      float q0 = qb[(t0 + 0) * 100 + d], q1 = qb[(t0 + 1) * 100 + d];
      float q2 = qb[(t0 + 2) * 100 + d], q3 = qb[(t0 + 3) * 100 + d];
      float k0 = kb[(s0 + 0) * 100 + d], k1 = kb[(s0 + 1) * 100 + d];
      float k2 = kb[(s0 + 2) * 100 + d], k3 = kb[(s0 + 3) * 100 + d];
      acc[0][0] += q0 * k0; acc[0][1] += q0 * k1; acc[0][2] += q0 * k2; acc[0][3] += q0 * k3;
      acc[1][0] += q1 * k0; acc[1][1] += q1 * k1; acc[1][2] += q1 * k2; acc[1][3] += q1 * k3;
      acc[2][0] += q2 * k0; acc[2][1] += q2 * k1; acc[2][2] += q2 * k2; acc[2][3] += q2 * k3;
      acc[3][0] += q3 * k0; acc[3][1] += q3 * k1; acc[3][2] += q3 * k2; acc[3][3] += q3 * k3;
    }
    const float sscale = 0.17677669529663687f;
    #pragma unroll
    for (int i = 0; i < 4; ++i) {
      if (t0 + i < NT) {
        #pragma unroll
        for (int j = 0; j < 4; ++j)
          sc[(hh * NT + t0 + i) * 52 + s0 + j] = acc[i][j] * sscale;
      }
    }
  }
  __syncthreads();

  // softmax per (head, t) row over s<49
  if (tid < 3 * NT) {
    float* row = sc + tid * 52;
    float m = row[0];
    for (int s = 1; s < NT; ++s) m = fmaxf(m, row[s]);
    float sum = 0.f;
    for (int s = 0; s < NT; ++s) { float e = __expf(row[s] - m); row[s] = e; sum += e; }
    float inv = 1.f / sum;
    for (int s = 0; s < NT; ++s) row[s] *= inv;
  }
  __syncthreads();

  // PV: out[t][h*32+d] = sum_s P[h][t][s] * v[s][h*32+d]  (into sy rows<49)
  for (int tile = tid; tile < 312; tile += 256) {   // 13 t-tiles x 24 c-tiles
    int tt = tile / 24, ct = tile - tt * 24;
    int t0 = tt * 4, c0 = ct * 4, hh = c0 >> 5;
    float acc[4][4] = {};
    for (int s = 0; s < NT; ++s) {
      float p0 = sc[(hh * NT + t0 + 0) * 52 + s], p1 = sc[(hh * NT + t0 + 1) * 52 + s];
      float p2 = sc[(hh * NT + t0 + 2) * 52 + s], p3 = sc[(hh * NT + t0 + 3) * 52 + s];
      float v0 = sv[s * 100 + c0 + 0], v1 = sv[s * 100 + c0 + 1];
      float v2 = sv[s * 100 + c0 + 2], v3 = sv[s * 100 + c0 + 3];
      acc[0][0] += p0 * v0; acc[0][1] += p0 * v1; acc[0][2] += p0 * v2; acc[0][3] += p0 * v3;
      acc[1][0] += p1 * v0; acc[1][1] += p1 * v1; acc[1][2] += p1 * v2; acc[1][3] += p1 * v3;
      acc[2][0] += p2 * v0; acc[2][1] += p2 * v1; acc[2][2] += p2 * v2; acc[2][3] += p2 * v3;
      acc[3][0] += p3 * v0; acc[3][1] += p3 * v1; acc[3][2] += p3 * v2; acc[3][3] += p3 * v3;
    }
    #pragma unroll
    for (int i = 0; i < 4; ++i) {
      if (t0 + i < NT) {
        #pragma unroll
        for (int j = 0; j < 4; ++j) sy[(t0 + i) * 100 + c0 + j] = acc[i][j];
      }
    }
  }
  __syncthreads();

  // stage proj_w into su (scores dead now)
  for (int idx = tid; idx < NC * NC; idx += 256) {
    int o = idx / NC, c = idx - o * NC;
    su[o * 97 + c] = proj_w[idx];
  }
  __syncthreads();

  // proj + bias + residual, scatter with per-window roll(+3,+3)
  {
    int bb = win >> 6, wl = win & 63;
    int hbase = (wl >> 3) * WSZ, wbase = (wl & 7) * WSZ;
    for (int tile = tid; tile < 312; tile += 256) {
      int tt = tile / 24, ct = tile - tt * 24;
      int t0 = tt * 4, c0 = ct * 4;
      float acc[4][4] = {};
      for (int c = 0; c < NC; ++c) {
        float a0 = sy[(t0 + 0) * 100 + c], a1 = sy[(t0 + 1) * 100 + c];
        float a2 = sy[(t0 + 2) * 100 + c], a3 = sy[(t0 + 3) * 100 + c];
        #pragma unroll
        for (int j = 0; j < 4; ++j) {
          float wv = su[(c0 + j) * 97 + c];
          acc[0][j] += a0 * wv; acc[1][j] += a1 * wv;
          acc[2][j] += a2 * wv; acc[3][j] += a3 * wv;
        }
      }
      float pb0 = proj_b[c0 + 0], pb1 = proj_b[c0 + 1];
      float pb2 = proj_b[c0 + 2], pb3 = proj_b[c0 + 3];
      #pragma unroll
      for (int i = 0; i < 4; ++i) {
        int t = t0 + i;
        if (t < NT) {
          int r = t / WSZ, q = t - r * WSZ;
          int rr = r + SSH; if (rr >= WSZ) rr -= WSZ;
          int qq = q + SSH; if (qq >= WSZ) qq -= WSZ;
          size_t tok = (size_t)bb * NL + (size_t)(hbase + rr) * NWW + (wbase + qq);
          const float4 xr = *reinterpret_cast<const float4*>(x + tok * NC + c0);
          float4 o4;
          o4.x = xr.x + acc[i][0] + pb0;
          o4.y = xr.y + acc[i][1] + pb1;
          o4.z = xr.z + acc[i][2] + pb2;
          o4.w = xr.w + acc[i][3] + pb3;
          *reinterpret_cast<float4*>(&x1[tok * NC + c0]) = o4;
        }
      }
    }
  }
}

// ---------------- K3: z = LN(LN(x1, n2g,n2b), fg,fb) ----------------
__global__ __launch_bounds__(256) void k3_ln2(const float* __restrict__ x1,
                                              const float* __restrict__ g2,
                                              const float* __restrict__ bb2,
                                              const float* __restrict__ gf,
                                              const float* __restrict__ bfn,
                                              float* __restrict__ z) {
  int lane = threadIdx.x & 63;
  int token = (blockIdx.x << 2) + (threadIdx.x >> 6);
  const float* xp = x1 + (size_t)token * NC;
  float v0 = xp[lane];
  float v1 = (lane < 32) ? xp[64 + lane] : 0.f;
  float mean = wsum(v0 + v1) * (1.f / 96.f);
  float d0 = v0 - mean, d1 = (lane < 32) ? (v1 - mean) : 0.f;
  float var = wsum(d0 * d0 + d1 * d1) * (1.f / 96.f);
  float rstd = rsqrtf(var + 1e-5f);
  float t0 = d0 * rstd * g2[lane] + bb2[lane];
  float t1 = (lane < 32) ? (d1 * rstd * g2[64 + lane] + bb2[64 + lane]) : 0.f;
  float mean2 = wsum(t0 + t1) * (1.f / 96.f);
  float e0 = t0 - mean2, e1 = (lane < 32) ? (t1 - mean2) : 0.f;
  float var2 = wsum(e0 * e0 + e1 * e1) * (1.f / 96.f);
  float rstd2 = rsqrtf(var2 + 1e-5f);
  float* zp = z + (size_t)token * NC;
  zp[lane] = e0 * rstd2 * gf[lane] + bfn[lane];
  if (lane < 32) zp[64 + lane] = e1 * rstd2 * gf[64 + lane] + bfn[64 + lane];
}

// ---------------- K4: TM-FFN (pin -> sigmoid -> log-lits -> clause GEMM -> exp -> tm_out -> blend) ----------------
// 16 tokens per block. LDS 76,928 B -> 2 blocks/CU.
__global__ __launch_bounds__(256) void k4_ffn(const float* __restrict__ z,
                                              const float* __restrict__ x1,
                                              const float* __restrict__ pin_w,
                                              const float* __restrict__ pin_b,
                                              const unsigned char* __restrict__ mask,
                                              const float* __restrict__ tm_out,
                                              const float* __restrict__ gate,
                                              float* __restrict__ out) {
  __shared__ float zt[16 * 100];          // z tile, later reused for logits
  __shared__ u16   lit[16 * 776];         // bf16 log-literals [t][j], j<768
  __shared__ float cla[16 * 132];         // clause values
  __shared__ float ubuf[9312];            // union: pin_w chunk (96x97 f32) / mask chunk (64x128 u8)
  unsigned char* mch = reinterpret_cast<unsigned char*>(ubuf);
  const int tid = threadIdx.x;
  const size_t tok0 = (size_t)blockIdx.x * 16;

  for (int idx = tid; idx < 16 * NC; idx += 256) {
    int t = idx / NC, c = idx - t * NC;
    zt[t * 100 + c] = z[(tok0 + t) * NC + c];
  }

  // pin gemm in 4 chunks of 96 output rows; y=sigmoid; store bf16 log-lits
  for (int och = 0; och < 4; ++och) {
    const int obase = och * 96;
    for (int idx = tid; idx < 96 * NC; idx += 256) {
      int o = idx / NC, c = idx - o * NC;
      ubuf[o * 97 + c] = pin_w[(size_t)(obase + o) * NC + c];
    }
    __syncthreads();
    if (tid < 192) {                           // 8 t-tiles x 24 o-tiles of (2t x 4o)
      int tt = tid / 24, ot = tid - tt * 24;
      int t0 = tt * 2, o0 = ot * 4;
      float acc[2][4] = {};
      for (int c = 0; c < NC; ++c) {
        float a0 = zt[(t0 + 0) * 100 + c], a1 = zt[(t0 + 1) * 100 + c];
        #pragma unroll
        for (int j = 0; j < 4; ++j) {
          float wv = ubuf[(o0 + j) * 97 + c];
          acc[0][j] += a0 * wv; acc[1][j] += a1 * wv;
        }
      }
      #pragma unroll
      for (int j = 0; j < 4; ++j) {
        int o = obase + o0 + j;
        float bias = pin_b[o];
        #pragma unroll
        for (int i = 0; i < 2; ++i) {
          float y = sigmoidf_(acc[i][j] + bias);
          lit[(t0 + i) * 776 + o]       = f2us(__logf(fmaxf(y, EPS_)));
          lit[(t0 + i) * 776 + 384 + o] = f2us(__logf(fmaxf(1.f - y, EPS_)));
        }
      }
    }
    __syncthreads();
  }

  // clause gemm: cla[t][k] = exp( sum_j lit[t][j] * mask[j][k] )
  const int ctt = tid >> 5, ckt = tid & 31;    // (2t x 4k) per thread
  const int t0c = ctt * 2, k0c = ckt * 4;
  float ca[2][4] = {};
  for (int j0 = 0; j0 < NLIT; j0 += 64) {
    for (int idx = tid; idx < 2048; idx += 256)
      reinterpret_cast<u32*>(mch)[idx] =
          reinterpret_cast<const u32*>(mask + (size_t)j0 * NCL_)[idx];
    __syncthreads();
    for (int jj = 0; jj < 64; ++jj) {
      float l0 = us2f(lit[(t0c + 0) * 776 + j0 + jj]);
      float l1 = us2f(lit[(t0c + 1) * 776 + j0 + jj]);
      uchar4 m4 = *reinterpret_cast<const uchar4*>(&mch[jj * 128 + k0c]);
      float m0 = (float)m4.x, m1 = (float)m4.y, m2 = (float)m4.z, m3 = (float)m4.w;
      ca[0][0] += l0 * m0; ca[0][1] += l0 * m1; ca[0][2] += l0 * m2; ca[0][3] += l0 * m3;
      ca[1][0] += l1 * m0; ca[1][1] += l1 * m1; ca[1][2] += l1 * m2; ca[1][3] += l1 * m3;
    }
    __syncthreads();
  }
  #pragma unroll
  for (int q = 0; q < 4; ++q) {
    cla[(t0c + 0) * 132 + k0c + q] = __expf(ca[0][q]);
    cla[(t0c + 1) * 132 + k0c + q] = __expf(ca[1][q]);
  }
  __syncthreads();

  // logits = cla @ tm_out  (into zt, reused)
  for (int tile = tid; tile < 96; tile += 256) {   // 4 t-tiles x 24 c-tiles
    int tt = tile / 24, ct = tile - tt * 24;
    int t0 = tt * 4, c0 = ct * 4;
    float acc[4][4] = {};
    for (int k = 0; k < NCL_; ++k) {
      float p0 = cla[(t0 + 0) * 132 + k], p1 = cla[(t0 + 1) * 132 + k];
      float p2 = cla[(t0 + 2) * 132 + k], p3 = cla[(t0 + 3) * 132 + k];
      const float4 wr = *reinterpret_cast<const float4*>(tm_out + (size_t)k * NC + c0);
      acc[0][0] += p0 * wr.x; acc[0][1] += p0 * wr.y; acc[0][2] += p0 * wr.z; acc[0][3] += p0 * wr.w;
      acc[1][0] += p1 * wr.x; acc[1][1] += p1 * wr.y; acc[1][2] += p1 * wr.z; acc[1][3] += p1 * wr.w;
      acc[2][0] += p2 * wr.x; acc[2][1] += p2 * wr.y; acc[2][2] += p2 * wr.z; acc[2][3] += p2 * wr.w;
      acc[3][0] += p3 * wr.x; acc[3][1] += p3 * wr.y; acc[3][2] += p3 * wr.z; acc[3][3] += p3 * wr.w;
    }
    #pragma unroll
    for (int i = 0; i < 4; ++i)
      #pragma unroll
      for (int j = 0; j < 4; ++j)
        zt[(t0 + i) * 100 + c0 + j] = acc[i][j];
  }
  __syncthreads();

  // blend + residual, write f32
  float gv = sigmoidf_(gate[0]);
  for (int idx = tid; idx < 16 * NC; idx += 256) {
    int t = idx / NC, c = idx - t * NC;
    float lg = zt[t * 100 + c];
    float val = x1[(tok0 + t) * NC + c] + gv * lg + (1.f - gv) * sigmoidf_(lg);
    out[(tok0 + t) * NC + c] = val;
  }
}

extern "C" void kernel_launch(void* const* d_in, const int* in_sizes, int n_in,
                              void* d_out, int out_size, void* d_ws, size_t ws_size,
                              hipStream_t stream) {
  (void)in_sizes; (void)n_in; (void)out_size; (void)ws_size;
  const float* x      = (const float*)d_in[0];
  const float* n1g    = (const float*)d_in[1];
  const float* n1b    = (const float*)d_in[2];
  const float* qkv_w  = (const float*)d_in[3];
  const float* qkv_b  = (const float*)d_in[4];
  const float* proj_w = (const float*)d_in[5];
  const float* proj_b = (const float*)d_in[6];
  const float* n2g    = (const float*)d_in[7];
  const float* n2b    = (const float*)d_in[8];
  const float* fng    = (const float*)d_in[9];
  const float* fnb    = (const float*)d_in[10];
  const float* pin_w  = (const float*)d_in[11];
  const float* pin_b  = (const float*)d_in[12];
  const float* tm_inc = (const float*)d_in[13];
  const float* tm_out = (const float*)d_in[14];
  const float* gate   = (const float*)d_in[15];

  float* wy = (float*)d_ws;                         // 50176*96 f32 (gathered LN1, reused as z)
  float* x1 = wy + (size_t)NTOK * NC;               // 50176*96 f32
  unsigned char* mask = (unsigned char*)(x1 + (size_t)NTOK * NC);  // 768*128 u8

  hipLaunchKernelGGL(k0_mask, dim3(384), dim3(256), 0, stream, tm_inc, mask);
  hipLaunchKernelGGL(k1_ln_gather, dim3(NTOK / 4), dim3(256), 0, stream, x, n1g, n1b, wy);
  hipLaunchKernelGGL(k2_attn, dim3(NWIN), dim3(256), 0, stream,
                     wy, qkv_w, qkv_b, proj_w, proj_b, x, x1);
  hipLaunchKernelGGL(k3_ln2, dim3(NTOK / 4), dim3(256), 0, stream, x1, n2g, n2b, fng, fnb, wy);
  hipLaunchKernelGGL(k4_ffn, dim3(NTOK / 16), dim3(256), 0, stream,
                     wy, x1, pin_w, pin_b, mask, tm_out, gate, (float*)d_out);
}

// Round 3
// 472.795 us; speedup vs baseline: 1.8312x; 1.8312x over previous
//
#include <hip/hip_runtime.h>

// ---- problem constants (B,H0,W0,C)=(16,56,56,96), NH=3, WS=7, SS=3, HID=384, NCL=128 ----
#define NB 16
#define NHH 56
#define NWW 56
#define NC 96
#define NL (NHH*NWW)          // 3136
#define NTOK (NB*NL)          // 50176
#define WSZ 7
#define NT 49                 // tokens per window
#define SSH 3
#define NWIN 1024             // 16 * 8 * 8
#define HDIM 32
#define HID_ 384
#define NCL_ 128
#define NLIT 768
#define EPS_ 1e-6f

typedef unsigned short u16;
typedef unsigned int   u32;
typedef __attribute__((ext_vector_type(8))) short short8;   // 8 bf16 (4 VGPRs)
typedef __attribute__((ext_vector_type(4))) float f32x4;    // MFMA C/D

__device__ __forceinline__ float us2f(u16 u) {
  union { u32 u; float f; } x; x.u = ((u32)u) << 16; return x.f;
}
__device__ __forceinline__ u16 f2us(float f) {   // RNE float->bf16
  union { float f; u32 u; } x; x.f = f;
  u32 lsb = (x.u >> 16) & 1u;
  return (u16)((x.u + 0x7fffu + lsb) >> 16);
}
__device__ __forceinline__ float wsum(float v) {
  #pragma unroll
  for (int off = 32; off > 0; off >>= 1) v += __shfl_down(v, off, 64);
  return __shfl(v, 0, 64);
}
__device__ __forceinline__ float sigmoidf_(float x) { return 1.f / (1.f + __expf(-x)); }

// ---------------- K0: build bf16 constants ----------------
// maskb[k][j] = 1.0/0.0 bf16  (native tm_inc layout [128][768])
// pinwb[o][c] = bf16(pin_w)   [384][96]
// tmoT[c][k]  = bf16(tm_out[k][c])  [96][128]
__global__ __launch_bounds__(256) void k0_prep(const float* __restrict__ tm_inc,
                                               const float* __restrict__ pin_w,
                                               const float* __restrict__ tm_out,
                                               u16* __restrict__ maskb,
                                               u16* __restrict__ pinwb,
                                               u16* __restrict__ tmoT) {
  int idx = blockIdx.x * 256 + threadIdx.x;
  if (idx < NCL_ * NLIT)
    maskb[idx] = (tm_inc[idx] > 0.f) ? (u16)0x3F80 : (u16)0;
  if (idx < HID_ * NC)
    pinwb[idx] = f2us(pin_w[idx]);
  if (idx < NC * NCL_) {
    int c = idx / NCL_, k = idx - c * NCL_;
    tmoT[idx] = f2us(tm_out[(size_t)k * NC + c]);
  }
}

// ---------------- K1: LN1 + global roll(-3,-3) + window gather ----------------
__global__ __launch_bounds__(256) void k1_ln_gather(const float* __restrict__ x,
                                                    const float* __restrict__ g,
                                                    const float* __restrict__ b,
                                                    float* __restrict__ wy) {
  int lane = threadIdx.x & 63;
  int token = (blockIdx.x << 2) + (threadIdx.x >> 6);
  const float* xp = x + (size_t)token * NC;
  float v0 = xp[lane];
  float v1 = (lane < 32) ? xp[64 + lane] : 0.f;
  float mean = wsum(v0 + v1) * (1.f / 96.f);
  float d0 = v0 - mean;
  float d1 = (lane < 32) ? (v1 - mean) : 0.f;
  float var = wsum(d0 * d0 + d1 * d1) * (1.f / 96.f);
  float rstd = rsqrtf(var + 1e-5f);
  int bb = token / NL, l = token - bb * NL;
  int h = l / NWW, w = l - h * NWW;
  int hp = h - SSH; if (hp < 0) hp += NHH;
  int wp = w - SSH; if (wp < 0) wp += NWW;
  int win = bb * 64 + (hp / WSZ) * 8 + (wp / WSZ);
  int tw = (hp % WSZ) * WSZ + (wp % WSZ);
  float* dst = wy + ((size_t)win * NT + tw) * NC;
  dst[lane] = d0 * rstd * g[lane] + b[lane];
  if (lane < 32) dst[64 + lane] = d1 * rstd * g[64 + lane] + b[64 + lane];
}

// ---------------- K2: per-window QKV + attention + proj + residual scatter ----------------
__global__ __launch_bounds__(256) void k2_attn(const float* __restrict__ wy,
                                               const float* __restrict__ qkv_w,
                                               const float* __restrict__ qkv_b,
                                               const float* __restrict__ proj_w,
                                               const float* __restrict__ proj_b,
                                               const float* __restrict__ x,
                                               float* __restrict__ x1) {
  __shared__ float smem[30112];   // 120,448 B
  float* sy = smem;
  float* sq = smem + 5200;
  float* sk = smem + 10400;
  float* sv = smem + 15600;
  float* su = smem + 20800;
  const int tid = threadIdx.x;
  const int win = blockIdx.x;

  for (int idx = tid; idx < 52 * NC; idx += 256) {
    int t = idx / NC, c = idx - t * NC;
    sy[t * 100 + c] = (t < NT) ? wy[((size_t)win * NT + t) * NC + c] : 0.f;
  }

  for (int part = 0; part < 3; ++part) {
    for (int idx = tid; idx < NC * NC; idx += 256) {
      int o = idx / NC, c = idx - o * NC;
      su[o * 97 + c] = qkv_w[(size_t)(part * NC + o) * NC + c];
    }
    __syncthreads();
    float* dst = (part == 0) ? sq : (part == 1) ? sk : sv;
    for (int tile = tid; tile < 312; tile += 256) {
      int tt = tile / 24, ot = tile - tt * 24;
      int t0 = tt * 4, o0 = ot * 4;
      float acc[4][4] = {};
      for (int c = 0; c < NC; ++c) {
        float a0 = sy[(t0 + 0) * 100 + c], a1 = sy[(t0 + 1) * 100 + c];
        float a2 = sy[(t0 + 2) * 100 + c], a3 = sy[(t0 + 3) * 100 + c];
        #pragma unroll
        for (int j = 0; j < 4; ++j) {
          float wv = su[(o0 + j) * 97 + c];
          acc[0][j] += a0 * wv; acc[1][j] += a1 * wv;
          acc[2][j] += a2 * wv; acc[3][j] += a3 * wv;
        }
      }
      #pragma unroll
      for (int j = 0; j < 4; ++j) {
        float bias = qkv_b[part * NC + o0 + j];
        #pragma unroll
        for (int i = 0; i < 4; ++i)
          dst[(t0 + i) * 100 + o0 + j] = (t0 + i < NT) ? (acc[i][j] + bias) : 0.f;
      }
    }
    __syncthreads();
  }

  float* sc = su;
  for (int tile = tid; tile < 507; tile += 256) {
    int hh = tile / 169, rem = tile - hh * 169;
    int rt = rem / 13;
    int t0 = rt * 4, s0 = (rem - rt * 13) * 4;
    const float* qb = sq + hh * HDIM;
    const float* kb = sk + hh * HDIM;
    float acc[4][4] = {};
    for (int d = 0; d < HDIM; ++d) {
      float q0 = qb[(t0 + 0) * 100 + d], q1 = qb[(t0 + 1) * 100 + d];
      float q2 = qb[(t0 + 2) * 100 + d], q3 = qb[(t0 + 3) * 100 + d];
      float k0 = kb[(s0 + 0) * 100 + d], k1 = kb[(s0 + 1) * 100 + d];
      float k2 = kb[(s0 + 2) * 100 + d], k3 = kb[(s0 + 3) * 100 + d];
      acc[0][0] += q0 * k0; acc[0][1] += q0 * k1; acc[0][2] += q0 * k2; acc[0][3] += q0 * k3;
      acc[1][0] += q1 * k0; acc[1][1] += q1 * k1; acc[1][2] += q1 * k2; acc[1][3] += q1 * k3;
      acc[2][0] += q2 * k0; acc[2][1] += q2 * k1; acc[2][2] += q2 * k2; acc[2][3] += q2 * k3;
      acc[3][0] += q3 * k0; acc[3][1] += q3 * k1; acc[3][2] += q3 * k2; acc[3][3] += q3 * k3;
    }
    const float sscale = 0.17677669529663687f;
    #pragma unroll
    for (int i = 0; i < 4; ++i) {
      if (t0 + i < NT) {
        #pragma unroll
        for (int j = 0; j < 4; ++j)
          sc[(hh * NT + t0 + i) * 52 + s0 + j] = acc[i][j] * sscale;
      }
    }
  }
  __syncthreads();

  if (tid < 3 * NT) {
    float* row = sc + tid * 52;
    float m = row[0];
    for (int s = 1; s < NT; ++s) m = fmaxf(m, row[s]);
    float sum = 0.f;
    for (int s = 0; s < NT; ++s) { float e = __expf(row[s] - m); row[s] = e; sum += e; }
    float inv = 1.f / sum;
    for (int s = 0; s < NT; ++s) row[s] *= inv;
  }
  __syncthreads();

  for (int tile = tid; tile < 312; tile += 256) {
    int tt = tile / 24, ct = tile - tt * 24;
    int t0 = tt * 4, c0 = ct * 4, hh = c0 >> 5;
    float acc[4][4] = {};
    for (int s = 0; s < NT; ++s) {
      float p0 = sc[(hh * NT + t0 + 0) * 52 + s], p1 = sc[(hh * NT + t0 + 1) * 52 + s];
      float p2 = sc[(hh * NT + t0 + 2) * 52 + s], p3 = sc[(hh * NT + t0 + 3) * 52 + s];
      float v0 = sv[s * 100 + c0 + 0], v1 = sv[s * 100 + c0 + 1];
      float v2 = sv[s * 100 + c0 + 2], v3 = sv[s * 100 + c0 + 3];
      acc[0][0] += p0 * v0; acc[0][1] += p0 * v1; acc[0][2] += p0 * v2; acc[0][3] += p0 * v3;
      acc[1][0] += p1 * v0; acc[1][1] += p1 * v1; acc[1][2] += p1 * v2; acc[1][3] += p1 * v3;
      acc[2][0] += p2 * v0; acc[2][1] += p2 * v1; acc[2][2] += p2 * v2; acc[2][3] += p2 * v3;
      acc[3][0] += p3 * v0; acc[3][1] += p3 * v1; acc[3][2] += p3 * v2; acc[3][3] += p3 * v3;
    }
    #pragma unroll
    for (int i = 0; i < 4; ++i) {
      if (t0 + i < NT) {
        #pragma unroll
        for (int j = 0; j < 4; ++j) sy[(t0 + i) * 100 + c0 + j] = acc[i][j];
      }
    }
  }
  __syncthreads();

  for (int idx = tid; idx < NC * NC; idx += 256) {
    int o = idx / NC, c = idx - o * NC;
    su[o * 97 + c] = proj_w[idx];
  }
  __syncthreads();

  {
    int bb = win >> 6, wl = win & 63;
    int hbase = (wl >> 3) * WSZ, wbase = (wl & 7) * WSZ;
    for (int tile = tid; tile < 312; tile += 256) {
      int tt = tile / 24, ct = tile - tt * 24;
      int t0 = tt * 4, c0 = ct * 4;
      float acc[4][4] = {};
      for (int c = 0; c < NC; ++c) {
        float a0 = sy[(t0 + 0) * 100 + c], a1 = sy[(t0 + 1) * 100 + c];
        float a2 = sy[(t0 + 2) * 100 + c], a3 = sy[(t0 + 3) * 100 + c];
        #pragma unroll
        for (int j = 0; j < 4; ++j) {
          float wv = su[(c0 + j) * 97 + c];
          acc[0][j] += a0 * wv; acc[1][j] += a1 * wv;
          acc[2][j] += a2 * wv; acc[3][j] += a3 * wv;
        }
      }
      float pb0 = proj_b[c0 + 0], pb1 = proj_b[c0 + 1];
      float pb2 = proj_b[c0 + 2], pb3 = proj_b[c0 + 3];
      #pragma unroll
      for (int i = 0; i < 4; ++i) {
        int t = t0 + i;
        if (t < NT) {
          int r = t / WSZ, q = t - r * WSZ;
          int rr = r + SSH; if (rr >= WSZ) rr -= WSZ;
          int qq = q + SSH; if (qq >= WSZ) qq -= WSZ;
          size_t tok = (size_t)bb * NL + (size_t)(hbase + rr) * NWW + (wbase + qq);
          const float4 xr = *reinterpret_cast<const float4*>(x + tok * NC + c0);
          float4 o4;
          o4.x = xr.x + acc[i][0] + pb0;
          o4.y = xr.y + acc[i][1] + pb1;
          o4.z = xr.z + acc[i][2] + pb2;
          o4.w = xr.w + acc[i][3] + pb3;
          *reinterpret_cast<float4*>(&x1[tok * NC + c0]) = o4;
        }
      }
    }
  }
}

// ---------------- K3: z = bf16( LN(LN(x1)) ) ----------------
__global__ __launch_bounds__(256) void k3_ln2(const float* __restrict__ x1,
                                              const float* __restrict__ g2,
                                              const float* __restrict__ bb2,
                                              const float* __restrict__ gf,
                                              const float* __restrict__ bfn,
                                              u16* __restrict__ zb) {
  int lane = threadIdx.x & 63;
  int token = (blockIdx.x << 2) + (threadIdx.x >> 6);
  const float* xp = x1 + (size_t)token * NC;
  float v0 = xp[lane];
  float v1 = (lane < 32) ? xp[64 + lane] : 0.f;
  float mean = wsum(v0 + v1) * (1.f / 96.f);
  float d0 = v0 - mean, d1 = (lane < 32) ? (v1 - mean) : 0.f;
  float var = wsum(d0 * d0 + d1 * d1) * (1.f / 96.f);
  float rstd = rsqrtf(var + 1e-5f);
  float t0 = d0 * rstd * g2[lane] + bb2[lane];
  float t1 = (lane < 32) ? (d1 * rstd * g2[64 + lane] + bb2[64 + lane]) : 0.f;
  float mean2 = wsum(t0 + t1) * (1.f / 96.f);
  float e0 = t0 - mean2, e1 = (lane < 32) ? (t1 - mean2) : 0.f;
  float var2 = wsum(e0 * e0 + e1 * e1) * (1.f / 96.f);
  float rstd2 = rsqrtf(var2 + 1e-5f);
  u16* zp = zb + (size_t)token * NC;
  zp[lane] = f2us(e0 * rstd2 * gf[lane] + bfn[lane]);
  if (lane < 32) zp[64 + lane] = f2us(e1 * rstd2 * gf[64 + lane] + bfn[64 + lane]);
}

// ---------------- K4: TM-FFN via MFMA ----------------
// 16 tokens/block, 4 waves. A-frags: lane&15 = M row, k = (lane>>4)*8 + j (b128).
// B-frags: lane&15 = N col, k contiguous per lane (b128 from row-major [n][k] layout).
// C/D: col = lane&15 (N), row = (lane>>4)*4 + reg (M).
__global__ __launch_bounds__(256) void k4_ffn(const u16* __restrict__ zb,
                                              const float* __restrict__ x1,
                                              const u16* __restrict__ pinwb,
                                              const float* __restrict__ pin_b,
                                              const u16* __restrict__ maskb,
                                              const u16* __restrict__ tmoT,
                                              const float* __restrict__ gate,
                                              float* __restrict__ out) {
  __shared__ u16 lit[16 * 776];       // bf16 log-literals [t][j], stride 776 (2-way banks)
  __shared__ u16 claT[16 * 136];      // bf16 clauses [t][k], stride 136
  const int tid  = threadIdx.x;
  const int wave = tid >> 6;
  const int lane = tid & 63;
  const int l16  = lane & 15;
  const int quad = lane >> 4;
  const size_t tok0 = (size_t)blockIdx.x * 16;

  // ---- pin gemm: out[t][o] = z[t][:96] . pinw[o][:96]; 24 N-tiles, wave w -> tiles [6w,6w+6) ----
  short8 a3[3];
  #pragma unroll
  for (int ks = 0; ks < 3; ++ks)
    a3[ks] = *reinterpret_cast<const short8*>(zb + (tok0 + l16) * NC + quad * 8 + ks * 32);

  for (int i = 0; i < 6; ++i) {
    const int n0 = (wave * 6 + i) * 16;
    f32x4 acc = {0.f, 0.f, 0.f, 0.f};
    #pragma unroll
    for (int ks = 0; ks < 3; ++ks) {
      short8 bfrag = *reinterpret_cast<const short8*>(
          pinwb + (size_t)(n0 + l16) * NC + quad * 8 + ks * 32);
      acc = __builtin_amdgcn_mfma_f32_16x16x32_bf16(a3[ks], bfrag, acc, 0, 0, 0);
    }
    const int o = n0 + l16;
    const float pb = pin_b[o];
    #pragma unroll
    for (int r = 0; r < 4; ++r) {
      const int t = quad * 4 + r;
      float y = sigmoidf_(acc[r] + pb);
      lit[t * 776 + o]       = f2us(__logf(fmaxf(y, EPS_)));
      lit[t * 776 + 384 + o] = f2us(__logf(fmaxf(1.f - y, EPS_)));
    }
  }
  __syncthreads();

  // ---- clause gemm: cla[t][k] = exp( lit[t][:768] . maskb[k][:768] ); wave w -> clause tiles {2w,2w+1} ----
  {
    const int ct0 = wave * 2;
    f32x4 c0 = {0.f, 0.f, 0.f, 0.f}, c1 = {0.f, 0.f, 0.f, 0.f};
    for (int ks = 0; ks < 24; ++ks) {
      const int k0 = ks * 32 + quad * 8;
      short8 a = *reinterpret_cast<const short8*>(&lit[l16 * 776 + k0]);
      short8 b0 = *reinterpret_cast<const short8*>(
          maskb + (size_t)((ct0 + 0) * 16 + l16) * NLIT + k0);
      short8 b1 = *reinterpret_cast<const short8*>(
          maskb + (size_t)((ct0 + 1) * 16 + l16) * NLIT + k0);
      c0 = __builtin_amdgcn_mfma_f32_16x16x32_bf16(a, b0, c0, 0, 0, 0);
      c1 = __builtin_amdgcn_mfma_f32_16x16x32_bf16(a, b1, c1, 0, 0, 0);
    }
    #pragma unroll
    for (int r = 0; r < 4; ++r) {
      const int t = quad * 4 + r;
      claT[t * 136 + (ct0 + 0) * 16 + l16] = f2us(__expf(c0[r]));
      claT[t * 136 + (ct0 + 1) * 16 + l16] = f2us(__expf(c1[r]));
    }
  }
  __syncthreads();

  // ---- logits = cla @ tm_out (via tmoT[c][k]); 6 N-tiles strided over waves; fused epilogue ----
  const float gv = sigmoidf_(gate[0]);
  for (int nt = wave; nt < 6; nt += 4) {
    f32x4 acc = {0.f, 0.f, 0.f, 0.f};
    #pragma unroll
    for (int ks = 0; ks < 4; ++ks) {
      const int k0 = ks * 32 + quad * 8;
      short8 a = *reinterpret_cast<const short8*>(&claT[l16 * 136 + k0]);
      short8 b = *reinterpret_cast<const short8*>(
          tmoT + (size_t)(nt * 16 + l16) * NCL_ + k0);
      acc = __builtin_amdgcn_mfma_f32_16x16x32_bf16(a, b, acc, 0, 0, 0);
    }
    const int c = nt * 16 + l16;
    #pragma unroll
    for (int r = 0; r < 4; ++r) {
      const size_t tok = tok0 + quad * 4 + r;
      float lg = acc[r];
      out[tok * NC + c] = x1[tok * NC + c] + gv * lg + (1.f - gv) * sigmoidf_(lg);
    }
  }
}

extern "C" void kernel_launch(void* const* d_in, const int* in_sizes, int n_in,
                              void* d_out, int out_size, void* d_ws, size_t ws_size,
                              hipStream_t stream) {
  (void)in_sizes; (void)n_in; (void)out_size; (void)ws_size;
  const float* x      = (const float*)d_in[0];
  const float* n1g    = (const float*)d_in[1];
  const float* n1b    = (const float*)d_in[2];
  const float* qkv_w  = (const float*)d_in[3];
  const float* qkv_b  = (const float*)d_in[4];
  const float* proj_w = (const float*)d_in[5];
  const float* proj_b = (const float*)d_in[6];
  const float* n2g    = (const float*)d_in[7];
  const float* n2b    = (const float*)d_in[8];
  const float* fng    = (const float*)d_in[9];
  const float* fnb    = (const float*)d_in[10];
  const float* pin_w  = (const float*)d_in[11];
  const float* pin_b  = (const float*)d_in[12];
  const float* tm_inc = (const float*)d_in[13];
  const float* tm_out = (const float*)d_in[14];
  const float* gate   = (const float*)d_in[15];

  float* wy = (float*)d_ws;                         // NTOK*96 f32 (gathered LN1; reused as zb bf16)
  float* x1 = wy + (size_t)NTOK * NC;               // NTOK*96 f32
  u16* maskb = (u16*)(x1 + (size_t)NTOK * NC);      // 128*768 bf16
  u16* pinwb = maskb + NCL_ * NLIT;                 // 384*96 bf16
  u16* tmoT  = pinwb + HID_ * NC;                   // 96*128 bf16
  u16* zb    = (u16*)wy;                            // NTOK*96 bf16 (aliases wy, free after k2)

  hipLaunchKernelGGL(k0_prep, dim3(384), dim3(256), 0, stream,
                     tm_inc, pin_w, tm_out, maskb, pinwb, tmoT);
  hipLaunchKernelGGL(k1_ln_gather, dim3(NTOK / 4), dim3(256), 0, stream, x, n1g, n1b, wy);
  hipLaunchKernelGGL(k2_attn, dim3(NWIN), dim3(256), 0, stream,
                     wy, qkv_w, qkv_b, proj_w, proj_b, x, x1);
  hipLaunchKernelGGL(k3_ln2, dim3(NTOK / 4), dim3(256), 0, stream, x1, n2g, n2b, fng, fnb, zb);
  hipLaunchKernelGGL(k4_ffn, dim3(NTOK / 16), dim3(256), 0, stream,
                     zb, x1, pinwb, pin_b, maskb, tmoT, gate, (float*)d_out);
}

// Round 4
// 280.513 us; speedup vs baseline: 3.0865x; 1.6855x over previous
//
#include <hip/hip_runtime.h>

// ---- problem constants (B,H0,W0,C)=(16,56,56,96), NH=3, WS=7, SS=3, HID=384, NCL=128 ----
#define NB 16
#define NHH 56
#define NWW 56
#define NC 96
#define NL (NHH*NWW)          // 3136
#define NTOK (NB*NL)          // 50176
#define WSZ 7
#define NT 49                 // tokens per window
#define SSH 3
#define NWIN 1024             // 16 * 8 * 8
#define HDIM 32
#define HID_ 384
#define NCL_ 128
#define NLIT 768
#define EPS_ 1e-6f

typedef unsigned short u16;
typedef unsigned int   u32;
typedef __attribute__((ext_vector_type(8))) short short8;   // 8 bf16 (4 VGPRs)
typedef __attribute__((ext_vector_type(4))) float f32x4;    // MFMA C/D

__device__ __forceinline__ float us2f(u16 u) {
  union { u32 u; float f; } x; x.u = ((u32)u) << 16; return x.f;
}
__device__ __forceinline__ u16 f2us(float f) {   // RNE float->bf16
  union { float f; u32 u; } x; x.f = f;
  u32 lsb = (x.u >> 16) & 1u;
  return (u16)((x.u + 0x7fffu + lsb) >> 16);
}
__device__ __forceinline__ float wsum(float v) {
  #pragma unroll
  for (int off = 32; off > 0; off >>= 1) v += __shfl_down(v, off, 64);
  return __shfl(v, 0, 64);
}
__device__ __forceinline__ float sigmoidf_(float x) { return 1.f / (1.f + __expf(-x)); }

// ---------------- K0: build bf16 constants ----------------
__global__ __launch_bounds__(256) void k0_prep(const float* __restrict__ tm_inc,
                                               const float* __restrict__ pin_w,
                                               const float* __restrict__ tm_out,
                                               const float* __restrict__ qkv_w,
                                               const float* __restrict__ proj_w,
                                               u16* __restrict__ maskb,
                                               u16* __restrict__ pinwb,
                                               u16* __restrict__ tmoT,
                                               u16* __restrict__ qkvwb,
                                               u16* __restrict__ projwb) {
  int idx = blockIdx.x * 256 + threadIdx.x;
  if (idx < NCL_ * NLIT)
    maskb[idx] = (tm_inc[idx] > 0.f) ? (u16)0x3F80 : (u16)0;
  if (idx < HID_ * NC)
    pinwb[idx] = f2us(pin_w[idx]);
  if (idx < NC * NCL_) {
    int c = idx / NCL_, k = idx - c * NCL_;
    tmoT[idx] = f2us(tm_out[(size_t)k * NC + c]);
  }
  if (idx < 3 * NC * NC)
    qkvwb[idx] = f2us(qkv_w[idx]);
  if (idx < NC * NC)
    projwb[idx] = f2us(proj_w[idx]);
}

// ---------------- K1: LN1 + global roll(-3,-3) + window gather ----------------
__global__ __launch_bounds__(256) void k1_ln_gather(const float* __restrict__ x,
                                                    const float* __restrict__ g,
                                                    const float* __restrict__ b,
                                                    float* __restrict__ wy) {
  int lane = threadIdx.x & 63;
  int token = (blockIdx.x << 2) + (threadIdx.x >> 6);
  const float* xp = x + (size_t)token * NC;
  float v0 = xp[lane];
  float v1 = (lane < 32) ? xp[64 + lane] : 0.f;
  float mean = wsum(v0 + v1) * (1.f / 96.f);
  float d0 = v0 - mean;
  float d1 = (lane < 32) ? (v1 - mean) : 0.f;
  float var = wsum(d0 * d0 + d1 * d1) * (1.f / 96.f);
  float rstd = rsqrtf(var + 1e-5f);
  int bb = token / NL, l = token - bb * NL;
  int h = l / NWW, w = l - h * NWW;
  int hp = h - SSH; if (hp < 0) hp += NHH;
  int wp = w - SSH; if (wp < 0) wp += NWW;
  int win = bb * 64 + (hp / WSZ) * 8 + (wp / WSZ);
  int tw = (hp % WSZ) * WSZ + (wp % WSZ);
  float* dst = wy + ((size_t)win * NT + tw) * NC;
  dst[lane] = d0 * rstd * g[lane] + b[lane];
  if (lane < 32) dst[64 + lane] = d1 * rstd * g[64 + lane] + b[64 + lane];
}

// ---------------- K2: per-window MFMA attention ----------------
// One block = one window. 4 waves; wave w owns M-tile (query rows 16w..16w+15).
// LDS (bf16): syb[64x104] y -> attn-out | sq[64x104] | sk[64x104] | svT[96x72] V^T | sp[4][16x72] P
// 62,976 B -> 2 blocks/CU. Strides 104/72 give 2-way bank aliasing (free).
// Barriers: 1 (y staged) + 2 (QKV written). Scores/softmax/PV/proj are wave-private.
__global__ __launch_bounds__(256) void k2_attn(const float* __restrict__ wy,
                                               const u16* __restrict__ qkvwb,
                                               const float* __restrict__ qkv_b,
                                               const u16* __restrict__ projwb,
                                               const float* __restrict__ proj_b,
                                               const float* __restrict__ x,
                                               float* __restrict__ x1) {
  __shared__ u16 syb[64 * 104];
  __shared__ u16 sq [64 * 104];
  __shared__ u16 sk [64 * 104];
  __shared__ u16 svT[96 * 72];
  __shared__ u16 sp [4 * 16 * 72];
  const int tid  = threadIdx.x;
  const int wave = tid >> 6;
  const int lane = tid & 63;
  const int l16  = lane & 15;
  const int quad = lane >> 4;
  const int win  = blockIdx.x;
  const int t0   = wave * 16;

  // stage y -> bf16 (rows 49..63 zero)
  for (int idx = tid; idx < 64 * NC; idx += 256) {
    int t = idx / NC, c = idx - t * NC;
    syb[t * 104 + c] = (t < NT) ? f2us(wy[((size_t)win * NT + t) * NC + c]) : (u16)0;
  }
  __syncthreads();

  // ---- QKV: M=64, N=288 (18 tiles), K=96 (3 steps). B-frags from global bf16 weights. ----
  {
    short8 afr[3];
    #pragma unroll
    for (int ks = 0; ks < 3; ++ks)
      afr[ks] = *reinterpret_cast<const short8*>(&syb[(t0 + l16) * 104 + quad * 8 + ks * 32]);
    for (int nt = 0; nt < 18; ++nt) {
      const int n0 = nt * 16;
      f32x4 acc = {0.f, 0.f, 0.f, 0.f};
      #pragma unroll
      for (int ks = 0; ks < 3; ++ks) {
        short8 bfr = *reinterpret_cast<const short8*>(
            qkvwb + (size_t)(n0 + l16) * NC + quad * 8 + ks * 32);
        acc = __builtin_amdgcn_mfma_f32_16x16x32_bf16(afr[ks], bfr, acc, 0, 0, 0);
      }
      const float bias = qkv_b[n0 + l16];
      const int part = nt / 6;                 // 0=q 1=k 2=v
      const int oc = n0 - part * 96 + l16;
      if (part < 2) {
        u16* dst = (part == 0) ? sq : sk;
        #pragma unroll
        for (int r = 0; r < 4; ++r)
          dst[(t0 + quad * 4 + r) * 104 + oc] = f2us(acc[r] + bias);
      } else {
        #pragma unroll
        for (int r = 0; r < 4; ++r)
          svT[oc * 72 + (t0 + quad * 4 + r)] = f2us(acc[r] + bias);
      }
    }
  }
  __syncthreads();

  // ---- per head: scores (K=32, 1 MFMA per N-tile) -> in-register softmax -> PV ----
  u16* spw = sp + wave * 16 * 72;
  const float sscale = 0.17677669529663687f;
  for (int h = 0; h < 3; ++h) {
    const int d0 = h * HDIM;
    short8 qf = *reinterpret_cast<const short8*>(&sq[(t0 + l16) * 104 + d0 + quad * 8]);
    f32x4 s[4];
    #pragma unroll
    for (int nt = 0; nt < 4; ++nt) {
      short8 kf = *reinterpret_cast<const short8*>(&sk[(nt * 16 + l16) * 104 + d0 + quad * 8]);
      f32x4 a = {0.f, 0.f, 0.f, 0.f};
      s[nt] = __builtin_amdgcn_mfma_f32_16x16x32_bf16(qf, kf, a, 0, 0, 0);
    }
    #pragma unroll
    for (int nt = 0; nt < 4; ++nt)
      #pragma unroll
      for (int r = 0; r < 4; ++r) s[nt][r] *= sscale;
    if (l16 >= 1) {                       // key col 48+l16 >= 49 -> mask
      #pragma unroll
      for (int r = 0; r < 4; ++r) s[3][r] = -1e30f;
    }
    #pragma unroll
    for (int r = 0; r < 4; ++r) {
      float m = fmaxf(fmaxf(s[0][r], s[1][r]), fmaxf(s[2][r], s[3][r]));
      #pragma unroll
      for (int off = 8; off > 0; off >>= 1) m = fmaxf(m, __shfl_xor(m, off, 16));
      float e0 = __expf(s[0][r] - m), e1 = __expf(s[1][r] - m);
      float e2 = __expf(s[2][r] - m), e3 = __expf(s[3][r] - m);
      float sum = e0 + e1 + e2 + e3;
      #pragma unroll
      for (int off = 8; off > 0; off >>= 1) sum += __shfl_xor(sum, off, 16);
      float inv = 1.f / sum;
      const int row = quad * 4 + r;
      spw[row * 72 +      l16] = f2us(e0 * inv);
      spw[row * 72 + 16 + l16] = f2us(e1 * inv);
      spw[row * 72 + 32 + l16] = f2us(e2 * inv);
      spw[row * 72 + 48 + l16] = f2us(e3 * inv);
    }
    // PV: N = head cols (2 tiles), K = 64 keys (2 steps); padded keys have P=0
    short8 pa[2];
    pa[0] = *reinterpret_cast<const short8*>(&spw[l16 * 72 + quad * 8]);
    pa[1] = *reinterpret_cast<const short8*>(&spw[l16 * 72 + 32 + quad * 8]);
    #pragma unroll
    for (int nt = 0; nt < 2; ++nt) {
      const int c0 = d0 + nt * 16;
      f32x4 acc = {0.f, 0.f, 0.f, 0.f};
      #pragma unroll
      for (int ks = 0; ks < 2; ++ks) {
        short8 vb = *reinterpret_cast<const short8*>(&svT[(c0 + l16) * 72 + ks * 32 + quad * 8]);
        acc = __builtin_amdgcn_mfma_f32_16x16x32_bf16(pa[ks], vb, acc, 0, 0, 0);
      }
      #pragma unroll
      for (int r = 0; r < 4; ++r)
        syb[(t0 + quad * 4 + r) * 104 + c0 + l16] = f2us(acc[r]);   // attn-out (wave-own rows)
    }
  }

  // ---- proj: M-tile own rows, N=96 (6 tiles), K=96 (3 steps); fused residual + roll scatter ----
  {
    short8 aa[3];
    #pragma unroll
    for (int ks = 0; ks < 3; ++ks)
      aa[ks] = *reinterpret_cast<const short8*>(&syb[(t0 + l16) * 104 + quad * 8 + ks * 32]);
    const int bb = win >> 6, wl = win & 63;
    const int hbase = (wl >> 3) * WSZ, wbase = (wl & 7) * WSZ;
    for (int nt = 0; nt < 6; ++nt) {
      const int n0 = nt * 16;
      f32x4 acc = {0.f, 0.f, 0.f, 0.f};
      #pragma unroll
      for (int ks = 0; ks < 3; ++ks) {
        short8 bfr = *reinterpret_cast<const short8*>(
            projwb + (size_t)(n0 + l16) * NC + quad * 8 + ks * 32);
        acc = __builtin_amdgcn_mfma_f32_16x16x32_bf16(aa[ks], bfr, acc, 0, 0, 0);
      }
      const float pb = proj_b[n0 + l16];
      #pragma unroll
      for (int r = 0; r < 4; ++r) {
        const int t = t0 + quad * 4 + r;
        if (t < NT) {
          int rr = t / WSZ + SSH; if (rr >= WSZ) rr -= WSZ;
          int qq = t % WSZ + SSH; if (qq >= WSZ) qq -= WSZ;
          size_t tok = (size_t)bb * NL + (size_t)(hbase + rr) * NWW + (wbase + qq);
          x1[tok * NC + n0 + l16] = x[tok * NC + n0 + l16] + acc[r] + pb;
        }
      }
    }
  }
}

// ---------------- K3: z = bf16( LN(LN(x1)) ) ----------------
__global__ __launch_bounds__(256) void k3_ln2(const float* __restrict__ x1,
                                              const float* __restrict__ g2,
                                              const float* __restrict__ bb2,
                                              const float* __restrict__ gf,
                                              const float* __restrict__ bfn,
                                              u16* __restrict__ zb) {
  int lane = threadIdx.x & 63;
  int token = (blockIdx.x << 2) + (threadIdx.x >> 6);
  const float* xp = x1 + (size_t)token * NC;
  float v0 = xp[lane];
  float v1 = (lane < 32) ? xp[64 + lane] : 0.f;
  float mean = wsum(v0 + v1) * (1.f / 96.f);
  float d0 = v0 - mean, d1 = (lane < 32) ? (v1 - mean) : 0.f;
  float var = wsum(d0 * d0 + d1 * d1) * (1.f / 96.f);
  float rstd = rsqrtf(var + 1e-5f);
  float t0 = d0 * rstd * g2[lane] + bb2[lane];
  float t1 = (lane < 32) ? (d1 * rstd * g2[64 + lane] + bb2[64 + lane]) : 0.f;
  float mean2 = wsum(t0 + t1) * (1.f / 96.f);
  float e0 = t0 - mean2, e1 = (lane < 32) ? (t1 - mean2) : 0.f;
  float var2 = wsum(e0 * e0 + e1 * e1) * (1.f / 96.f);
  float rstd2 = rsqrtf(var2 + 1e-5f);
  u16* zp = zb + (size_t)token * NC;
  zp[lane] = f2us(e0 * rstd2 * gf[lane] + bfn[lane]);
  if (lane < 32) zp[64 + lane] = f2us(e1 * rstd2 * gf[64 + lane] + bfn[64 + lane]);
}

// ---------------- K4: TM-FFN via MFMA ----------------
__global__ __launch_bounds__(256) void k4_ffn(const u16* __restrict__ zb,
                                              const float* __restrict__ x1,
                                              const u16* __restrict__ pinwb,
                                              const float* __restrict__ pin_b,
                                              const u16* __restrict__ maskb,
                                              const u16* __restrict__ tmoT,
                                              const float* __restrict__ gate,
                                              float* __restrict__ out) {
  __shared__ u16 lit[16 * 776];       // bf16 log-literals [t][j]
  __shared__ u16 claT[16 * 136];      // bf16 clauses [t][k]
  const int tid  = threadIdx.x;
  const int wave = tid >> 6;
  const int lane = tid & 63;
  const int l16  = lane & 15;
  const int quad = lane >> 4;
  const size_t tok0 = (size_t)blockIdx.x * 16;

  short8 a3[3];
  #pragma unroll
  for (int ks = 0; ks < 3; ++ks)
    a3[ks] = *reinterpret_cast<const short8*>(zb + (tok0 + l16) * NC + quad * 8 + ks * 32);

  for (int i = 0; i < 6; ++i) {
    const int n0 = (wave * 6 + i) * 16;
    f32x4 acc = {0.f, 0.f, 0.f, 0.f};
    #pragma unroll
    for (int ks = 0; ks < 3; ++ks) {
      short8 bfrag = *reinterpret_cast<const short8*>(
          pinwb + (size_t)(n0 + l16) * NC + quad * 8 + ks * 32);
      acc = __builtin_amdgcn_mfma_f32_16x16x32_bf16(a3[ks], bfrag, acc, 0, 0, 0);
    }
    const int o = n0 + l16;
    const float pb = pin_b[o];
    #pragma unroll
    for (int r = 0; r < 4; ++r) {
      const int t = quad * 4 + r;
      float y = sigmoidf_(acc[r] + pb);
      lit[t * 776 + o]       = f2us(__logf(fmaxf(y, EPS_)));
      lit[t * 776 + 384 + o] = f2us(__logf(fmaxf(1.f - y, EPS_)));
    }
  }
  __syncthreads();

  {
    const int ct0 = wave * 2;
    f32x4 c0 = {0.f, 0.f, 0.f, 0.f}, c1 = {0.f, 0.f, 0.f, 0.f};
    for (int ks = 0; ks < 24; ++ks) {
      const int k0 = ks * 32 + quad * 8;
      short8 a = *reinterpret_cast<const short8*>(&lit[l16 * 776 + k0]);
      short8 b0 = *reinterpret_cast<const short8*>(
          maskb + (size_t)((ct0 + 0) * 16 + l16) * NLIT + k0);
      short8 b1 = *reinterpret_cast<const short8*>(
          maskb + (size_t)((ct0 + 1) * 16 + l16) * NLIT + k0);
      c0 = __builtin_amdgcn_mfma_f32_16x16x32_bf16(a, b0, c0, 0, 0, 0);
      c1 = __builtin_amdgcn_mfma_f32_16x16x32_bf16(a, b1, c1, 0, 0, 0);
    }
    #pragma unroll
    for (int r = 0; r < 4; ++r) {
      const int t = quad * 4 + r;
      claT[t * 136 + (ct0 + 0) * 16 + l16] = f2us(__expf(c0[r]));
      claT[t * 136 + (ct0 + 1) * 16 + l16] = f2us(__expf(c1[r]));
    }
  }
  __syncthreads();

  const float gv = sigmoidf_(gate[0]);
  for (int nt = wave; nt < 6; nt += 4) {
    f32x4 acc = {0.f, 0.f, 0.f, 0.f};
    #pragma unroll
    for (int ks = 0; ks < 4; ++ks) {
      const int k0 = ks * 32 + quad * 8;
      short8 a = *reinterpret_cast<const short8*>(&claT[l16 * 136 + k0]);
      short8 b = *reinterpret_cast<const short8*>(
          tmoT + (size_t)(nt * 16 + l16) * NCL_ + k0);
      acc = __builtin_amdgcn_mfma_f32_16x16x32_bf16(a, b, acc, 0, 0, 0);
    }
    const int c = nt * 16 + l16;
    #pragma unroll
    for (int r = 0; r < 4; ++r) {
      const size_t tok = tok0 + quad * 4 + r;
      float lg = acc[r];
      out[tok * NC + c] = x1[tok * NC + c] + gv * lg + (1.f - gv) * sigmoidf_(lg);
    }
  }
}

extern "C" void kernel_launch(void* const* d_in, const int* in_sizes, int n_in,
                              void* d_out, int out_size, void* d_ws, size_t ws_size,
                              hipStream_t stream) {
  (void)in_sizes; (void)n_in; (void)out_size; (void)ws_size;
  const float* x      = (const float*)d_in[0];
  const float* n1g    = (const float*)d_in[1];
  const float* n1b    = (const float*)d_in[2];
  const float* qkv_w  = (const float*)d_in[3];
  const float* qkv_b  = (const float*)d_in[4];
  const float* proj_w = (const float*)d_in[5];
  const float* proj_b = (const float*)d_in[6];
  const float* n2g    = (const float*)d_in[7];
  const float* n2b    = (const float*)d_in[8];
  const float* fng    = (const float*)d_in[9];
  const float* fnb    = (const float*)d_in[10];
  const float* pin_w  = (const float*)d_in[11];
  const float* pin_b  = (const float*)d_in[12];
  const float* tm_inc = (const float*)d_in[13];
  const float* tm_out = (const float*)d_in[14];
  const float* gate   = (const float*)d_in[15];

  float* wy = (float*)d_ws;                         // NTOK*96 f32 (gathered LN1; reused as zb bf16)
  float* x1 = wy + (size_t)NTOK * NC;               // NTOK*96 f32
  u16* maskb = (u16*)(x1 + (size_t)NTOK * NC);      // 128*768 bf16
  u16* pinwb = maskb + NCL_ * NLIT;                 // 384*96 bf16
  u16* tmoT  = pinwb + HID_ * NC;                   // 96*128 bf16
  u16* qkvwb = tmoT + NC * NCL_;                    // 288*96 bf16
  u16* projwb= qkvwb + 3 * NC * NC;                 // 96*96 bf16
  u16* zb    = (u16*)wy;                            // NTOK*96 bf16 (aliases wy, free after k2)

  hipLaunchKernelGGL(k0_prep, dim3(384), dim3(256), 0, stream,
                     tm_inc, pin_w, tm_out, qkv_w, proj_w, maskb, pinwb, tmoT, qkvwb, projwb);
  hipLaunchKernelGGL(k1_ln_gather, dim3(NTOK / 4), dim3(256), 0, stream, x, n1g, n1b, wy);
  hipLaunchKernelGGL(k2_attn, dim3(NWIN), dim3(256), 0, stream,
                     wy, qkvwb, qkv_b, projwb, proj_b, x, x1);
  hipLaunchKernelGGL(k3_ln2, dim3(NTOK / 4), dim3(256), 0, stream, x1, n2g, n2b, fng, fnb, zb);
  hipLaunchKernelGGL(k4_ffn, dim3(NTOK / 16), dim3(256), 0, stream,
                     zb, x1, pinwb, pin_b, maskb, tmoT, gate, (float*)d_out);
}

// Round 6
// 256.242 us; speedup vs baseline: 3.3788x; 1.0947x over previous
//
#include <hip/hip_runtime.h>

// ---- problem constants (B,H0,W0,C)=(16,56,56,96), NH=3, WS=7, SS=3, HID=384, NCL=128 ----
#define NB 16
#define NHH 56
#define NWW 56
#define NC 96
#define NL (NHH*NWW)          // 3136
#define NTOK (NB*NL)          // 50176
#define WSZ 7
#define NT 49                 // tokens per window
#define SSH 3
#define NWIN 1024             // 16 * 8 * 8
#define HDIM 32
#define HID_ 384
#define NCL_ 128
#define NLIT 768
#define EPS_ 1e-6f

typedef unsigned short u16;
typedef unsigned int   u32;
typedef __attribute__((ext_vector_type(8))) short short8;   // 8 bf16 (4 VGPRs)
typedef __attribute__((ext_vector_type(4))) float f32x4;    // MFMA C/D

__device__ __forceinline__ float us2f(u16 u) {
  union { u32 u; float f; } x; x.u = ((u32)u) << 16; return x.f;
}
__device__ __forceinline__ u16 f2us(float f) {   // RNE float->bf16
  union { float f; u32 u; } x; x.f = f;
  u32 lsb = (x.u >> 16) & 1u;
  return (u16)((x.u + 0x7fffu + lsb) >> 16);
}
__device__ __forceinline__ float wsum(float v) {
  #pragma unroll
  for (int off = 32; off > 0; off >>= 1) v += __shfl_down(v, off, 64);
  return __shfl(v, 0, 64);
}
__device__ __forceinline__ float sigmoidf_(float x) { return 1.f / (1.f + __expf(-x)); }

// ---------------- K0: build bf16 constants ----------------
__global__ __launch_bounds__(256) void k0_prep(const float* __restrict__ tm_inc,
                                               const float* __restrict__ pin_w,
                                               const float* __restrict__ tm_out,
                                               const float* __restrict__ qkv_w,
                                               const float* __restrict__ proj_w,
                                               u16* __restrict__ maskb,
                                               u16* __restrict__ pinwb,
                                               u16* __restrict__ tmoT,
                                               u16* __restrict__ qkvwb,
                                               u16* __restrict__ projwb) {
  int idx = blockIdx.x * 256 + threadIdx.x;
  if (idx < NCL_ * NLIT)
    maskb[idx] = (tm_inc[idx] > 0.f) ? (u16)0x3F80 : (u16)0;
  if (idx < HID_ * NC)
    pinwb[idx] = f2us(pin_w[idx]);
  if (idx < NC * NCL_) {
    int c = idx / NCL_, k = idx - c * NCL_;
    tmoT[idx] = f2us(tm_out[(size_t)k * NC + c]);
  }
  if (idx < 3 * NC * NC)
    qkvwb[idx] = f2us(qkv_w[idx]);
  if (idx < NC * NC)
    projwb[idx] = f2us(proj_w[idx]);
}

// ---------------- K2: LN1 + window gather + MFMA attention + proj + residual scatter ----------------
// One block = one window. 4 waves; wave w owns query rows 16w..16w+15.
__global__ __launch_bounds__(256) void k2_attn(const float* __restrict__ x,
                                               const float* __restrict__ n1g,
                                               const float* __restrict__ n1b,
                                               const u16* __restrict__ qkvwb,
                                               const float* __restrict__ qkv_b,
                                               const u16* __restrict__ projwb,
                                               const float* __restrict__ proj_b,
                                               float* __restrict__ x1) {
  __shared__ __align__(16) u16 syb[64 * 104];
  __shared__ __align__(16) u16 sq [64 * 104];
  __shared__ __align__(16) u16 sk [64 * 104];
  __shared__ __align__(16) u16 svT[96 * 72];
  __shared__ __align__(16) u16 sp [4 * 16 * 72];
  const int tid  = threadIdx.x;
  const int wave = tid >> 6;
  const int lane = tid & 63;
  const int l16  = lane & 15;
  const int quad = lane >> 4;
  const int win  = blockIdx.x;
  const int t0   = wave * 16;
  const int bb = win >> 6, wl = win & 63;
  const int hbase = (wl >> 3) * WSZ, wbase = (wl & 7) * WSZ;

  // ---- LN1 head: 4 threads per token; gather from x with inverse global roll ----
  {
    const int t = tid >> 2, s = tid & 3;
    if (t < NT) {
      int hp = hbase + t / WSZ, wp = wbase + t % WSZ;
      int h = hp + SSH; if (h >= NHH) h -= NHH;
      int w = wp + SSH; if (w >= NWW) w -= NWW;
      const float* xp = x + ((size_t)bb * NL + (size_t)h * NWW + w) * NC;
      float4 v[6];
      float sum = 0.f;
      #pragma unroll
      for (int k = 0; k < 6; ++k) {
        v[k] = *reinterpret_cast<const float4*>(xp + s * 4 + k * 16);
        sum += v[k].x + v[k].y + v[k].z + v[k].w;
      }
      sum += __shfl_xor(sum, 1); sum += __shfl_xor(sum, 2);
      float mean = sum * (1.f / 96.f);
      float ssq = 0.f;
      #pragma unroll
      for (int k = 0; k < 6; ++k) {
        float d0 = v[k].x - mean, d1 = v[k].y - mean;
        float d2 = v[k].z - mean, d3 = v[k].w - mean;
        ssq += d0 * d0 + d1 * d1 + d2 * d2 + d3 * d3;
      }
      ssq += __shfl_xor(ssq, 1); ssq += __shfl_xor(ssq, 2);
      float rstd = rsqrtf(ssq * (1.f / 96.f) + 1e-5f);
      #pragma unroll
      for (int k = 0; k < 6; ++k) {
        int c = s * 4 + k * 16;
        const float4 g4 = *reinterpret_cast<const float4*>(n1g + c);
        const float4 b4 = *reinterpret_cast<const float4*>(n1b + c);
        syb[t * 104 + c + 0] = f2us((v[k].x - mean) * rstd * g4.x + b4.x);
        syb[t * 104 + c + 1] = f2us((v[k].y - mean) * rstd * g4.y + b4.y);
        syb[t * 104 + c + 2] = f2us((v[k].z - mean) * rstd * g4.z + b4.z);
        syb[t * 104 + c + 3] = f2us((v[k].w - mean) * rstd * g4.w + b4.w);
      }
    } else {
      #pragma unroll
      for (int k = 0; k < 6; ++k) {
        int c = s * 4 + k * 16;
        syb[t * 104 + c + 0] = 0; syb[t * 104 + c + 1] = 0;
        syb[t * 104 + c + 2] = 0; syb[t * 104 + c + 3] = 0;
      }
    }
  }
  __syncthreads();

  // ---- QKV: M=64, N=288 (18 tiles), K=96 (3 steps) ----
  {
    short8 afr[3];
    #pragma unroll
    for (int ks = 0; ks < 3; ++ks)
      afr[ks] = *reinterpret_cast<const short8*>(&syb[(t0 + l16) * 104 + quad * 8 + ks * 32]);
    for (int nt = 0; nt < 18; ++nt) {
      const int n0 = nt * 16;
      f32x4 acc = {0.f, 0.f, 0.f, 0.f};
      #pragma unroll
      for (int ks = 0; ks < 3; ++ks) {
        short8 bfr = *reinterpret_cast<const short8*>(
            qkvwb + (size_t)(n0 + l16) * NC + quad * 8 + ks * 32);
        acc = __builtin_amdgcn_mfma_f32_16x16x32_bf16(afr[ks], bfr, acc, 0, 0, 0);
      }
      const float bias = qkv_b[n0 + l16];
      const int part = nt / 6;                 // 0=q 1=k 2=v
      const int oc = n0 - part * 96 + l16;
      if (part < 2) {
        u16* dst = (part == 0) ? sq : sk;
        #pragma unroll
        for (int r = 0; r < 4; ++r)
          dst[(t0 + quad * 4 + r) * 104 + oc] = f2us(acc[r] + bias);
      } else {
        #pragma unroll
        for (int r = 0; r < 4; ++r)
          svT[oc * 72 + (t0 + quad * 4 + r)] = f2us(acc[r] + bias);
      }
    }
  }
  __syncthreads();

  // ---- per head: scores -> in-register softmax -> PV (all wave-private) ----
  u16* spw = sp + wave * 16 * 72;
  const float sscale = 0.17677669529663687f;
  for (int h = 0; h < 3; ++h) {
    const int d0 = h * HDIM;
    short8 qf = *reinterpret_cast<const short8*>(&sq[(t0 + l16) * 104 + d0 + quad * 8]);
    f32x4 s[4];
    #pragma unroll
    for (int nt = 0; nt < 4; ++nt) {
      short8 kf = *reinterpret_cast<const short8*>(&sk[(nt * 16 + l16) * 104 + d0 + quad * 8]);
      f32x4 a = {0.f, 0.f, 0.f, 0.f};
      s[nt] = __builtin_amdgcn_mfma_f32_16x16x32_bf16(qf, kf, a, 0, 0, 0);
    }
    #pragma unroll
    for (int nt = 0; nt < 4; ++nt)
      #pragma unroll
      for (int r = 0; r < 4; ++r) s[nt][r] *= sscale;
    if (l16 >= 1) {                       // key col 48+l16 >= 49 -> mask
      #pragma unroll
      for (int r = 0; r < 4; ++r) s[3][r] = -1e30f;
    }
    #pragma unroll
    for (int r = 0; r < 4; ++r) {
      float m = fmaxf(fmaxf(s[0][r], s[1][r]), fmaxf(s[2][r], s[3][r]));
      #pragma unroll
      for (int off = 8; off > 0; off >>= 1) m = fmaxf(m, __shfl_xor(m, off, 16));
      float e0 = __expf(s[0][r] - m), e1 = __expf(s[1][r] - m);
      float e2 = __expf(s[2][r] - m), e3 = __expf(s[3][r] - m);
      float sum = e0 + e1 + e2 + e3;
      #pragma unroll
      for (int off = 8; off > 0; off >>= 1) sum += __shfl_xor(sum, off, 16);
      float inv = 1.f / sum;
      const int row = quad * 4 + r;
      spw[row * 72 +      l16] = f2us(e0 * inv);
      spw[row * 72 + 16 + l16] = f2us(e1 * inv);
      spw[row * 72 + 32 + l16] = f2us(e2 * inv);
      spw[row * 72 + 48 + l16] = f2us(e3 * inv);
    }
    short8 pa[2];
    pa[0] = *reinterpret_cast<const short8*>(&spw[l16 * 72 + quad * 8]);
    pa[1] = *reinterpret_cast<const short8*>(&spw[l16 * 72 + 32 + quad * 8]);
    #pragma unroll
    for (int nt = 0; nt < 2; ++nt) {
      const int c0 = d0 + nt * 16;
      f32x4 acc = {0.f, 0.f, 0.f, 0.f};
      #pragma unroll
      for (int ks = 0; ks < 2; ++ks) {
        short8 vb = *reinterpret_cast<const short8*>(&svT[(c0 + l16) * 72 + ks * 32 + quad * 8]);
        acc = __builtin_amdgcn_mfma_f32_16x16x32_bf16(pa[ks], vb, acc, 0, 0, 0);
      }
      #pragma unroll
      for (int r = 0; r < 4; ++r)
        syb[(t0 + quad * 4 + r) * 104 + c0 + l16] = f2us(acc[r]);
    }
  }

  // ---- proj: N=96 (6 tiles), K=96 (3 steps); fused residual + per-window roll scatter ----
  {
    short8 aa[3];
    #pragma unroll
    for (int ks = 0; ks < 3; ++ks)
      aa[ks] = *reinterpret_cast<const short8*>(&syb[(t0 + l16) * 104 + quad * 8 + ks * 32]);
    for (int nt = 0; nt < 6; ++nt) {
      const int n0 = nt * 16;
      f32x4 acc = {0.f, 0.f, 0.f, 0.f};
      #pragma unroll
      for (int ks = 0; ks < 3; ++ks) {
        short8 bfr = *reinterpret_cast<const short8*>(
            projwb + (size_t)(n0 + l16) * NC + quad * 8 + ks * 32);
        acc = __builtin_amdgcn_mfma_f32_16x16x32_bf16(aa[ks], bfr, acc, 0, 0, 0);
      }
      const float pb = proj_b[n0 + l16];
      #pragma unroll
      for (int r = 0; r < 4; ++r) {
        const int t = t0 + quad * 4 + r;
        if (t < NT) {
          int rr = t / WSZ + SSH; if (rr >= WSZ) rr -= WSZ;
          int qq = t % WSZ + SSH; if (qq >= WSZ) qq -= WSZ;
          size_t tok = (size_t)bb * NL + (size_t)(hbase + rr) * NWW + (wbase + qq);
          x1[tok * NC + n0 + l16] = x[tok * NC + n0 + l16] + acc[r] + pb;
        }
      }
    }
  }
}

// ---------------- K3: z = bf16( LN(LN(x1)) )  [round-4 verbatim: two-pass, wave per token] ----------------
__global__ __launch_bounds__(256) void k3_ln2(const float* __restrict__ x1,
                                              const float* __restrict__ g2,
                                              const float* __restrict__ bb2,
                                              const float* __restrict__ gf,
                                              const float* __restrict__ bfn,
                                              u16* __restrict__ zb) {
  int lane = threadIdx.x & 63;
  int token = (blockIdx.x << 2) + (threadIdx.x >> 6);
  const float* xp = x1 + (size_t)token * NC;
  float v0 = xp[lane];
  float v1 = (lane < 32) ? xp[64 + lane] : 0.f;
  float mean = wsum(v0 + v1) * (1.f / 96.f);
  float d0 = v0 - mean, d1 = (lane < 32) ? (v1 - mean) : 0.f;
  float var = wsum(d0 * d0 + d1 * d1) * (1.f / 96.f);
  float rstd = rsqrtf(var + 1e-5f);
  float t0 = d0 * rstd * g2[lane] + bb2[lane];
  float t1 = (lane < 32) ? (d1 * rstd * g2[64 + lane] + bb2[64 + lane]) : 0.f;
  float mean2 = wsum(t0 + t1) * (1.f / 96.f);
  float e0 = t0 - mean2, e1 = (lane < 32) ? (t1 - mean2) : 0.f;
  float var2 = wsum(e0 * e0 + e1 * e1) * (1.f / 96.f);
  float rstd2 = rsqrtf(var2 + 1e-5f);
  u16* zp = zb + (size_t)token * NC;
  zp[lane] = f2us(e0 * rstd2 * gf[lane] + bfn[lane]);
  if (lane < 32) zp[64 + lane] = f2us(e1 * rstd2 * gf[64 + lane] + bfn[64 + lane]);
}

// ---------------- K4: TM-FFN via MFMA  [round-4 verbatim + unroll-4 clause loop] ----------------
__global__ __launch_bounds__(256) void k4_ffn(const u16* __restrict__ zb,
                                              const float* __restrict__ x1,
                                              const u16* __restrict__ pinwb,
                                              const float* __restrict__ pin_b,
                                              const u16* __restrict__ maskb,
                                              const u16* __restrict__ tmoT,
                                              const float* __restrict__ gate,
                                              float* __restrict__ out) {
  __shared__ __align__(16) u16 lit[16 * 776];       // bf16 log-literals [t][j]
  __shared__ __align__(16) u16 claT[16 * 136];      // bf16 clauses [t][k]
  const int tid  = threadIdx.x;
  const int wave = tid >> 6;
  const int lane = tid & 63;
  const int l16  = lane & 15;
  const int quad = lane >> 4;
  const size_t tok0 = (size_t)blockIdx.x * 16;

  short8 a3[3];
  #pragma unroll
  for (int ks = 0; ks < 3; ++ks)
    a3[ks] = *reinterpret_cast<const short8*>(zb + (tok0 + l16) * NC + quad * 8 + ks * 32);

  for (int i = 0; i < 6; ++i) {
    const int n0 = (wave * 6 + i) * 16;
    f32x4 acc = {0.f, 0.f, 0.f, 0.f};
    #pragma unroll
    for (int ks = 0; ks < 3; ++ks) {
      short8 bfrag = *reinterpret_cast<const short8*>(
          pinwb + (size_t)(n0 + l16) * NC + quad * 8 + ks * 32);
      acc = __builtin_amdgcn_mfma_f32_16x16x32_bf16(a3[ks], bfrag, acc, 0, 0, 0);
    }
    const int o = n0 + l16;
    const float pb = pin_b[o];
    #pragma unroll
    for (int r = 0; r < 4; ++r) {
      const int t = quad * 4 + r;
      float y = sigmoidf_(acc[r] + pb);
      lit[t * 776 + o]       = f2us(__logf(fmaxf(y, EPS_)));
      lit[t * 776 + 384 + o] = f2us(__logf(fmaxf(1.f - y, EPS_)));
    }
  }
  __syncthreads();

  {
    const int ct0 = wave * 2;
    f32x4 c0 = {0.f, 0.f, 0.f, 0.f}, c1 = {0.f, 0.f, 0.f, 0.f};
    #pragma unroll 4
    for (int ks = 0; ks < 24; ++ks) {
      const int k0 = ks * 32 + quad * 8;
      short8 a = *reinterpret_cast<const short8*>(&lit[l16 * 776 + k0]);
      short8 b0 = *reinterpret_cast<const short8*>(
          maskb + (size_t)((ct0 + 0) * 16 + l16) * NLIT + k0);
      short8 b1 = *reinterpret_cast<const short8*>(
          maskb + (size_t)((ct0 + 1) * 16 + l16) * NLIT + k0);
      c0 = __builtin_amdgcn_mfma_f32_16x16x32_bf16(a, b0, c0, 0, 0, 0);
      c1 = __builtin_amdgcn_mfma_f32_16x16x32_bf16(a, b1, c1, 0, 0, 0);
    }
    #pragma unroll
    for (int r = 0; r < 4; ++r) {
      const int t = quad * 4 + r;
      claT[t * 136 + (ct0 + 0) * 16 + l16] = f2us(__expf(c0[r]));
      claT[t * 136 + (ct0 + 1) * 16 + l16] = f2us(__expf(c1[r]));
    }
  }
  __syncthreads();

  const float gv = sigmoidf_(gate[0]);
  for (int nt = wave; nt < 6; nt += 4) {
    f32x4 acc = {0.f, 0.f, 0.f, 0.f};
    #pragma unroll
    for (int ks = 0; ks < 4; ++ks) {
      const int k0 = ks * 32 + quad * 8;
      short8 a = *reinterpret_cast<const short8*>(&claT[l16 * 136 + k0]);
      short8 b = *reinterpret_cast<const short8*>(
          tmoT + (size_t)(nt * 16 + l16) * NCL_ + k0);
      acc = __builtin_amdgcn_mfma_f32_16x16x32_bf16(a, b, acc, 0, 0, 0);
    }
    const int c = nt * 16 + l16;
    #pragma unroll
    for (int r = 0; r < 4; ++r) {
      const size_t tok = tok0 + quad * 4 + r;
      float lg = acc[r];
      out[tok * NC + c] = x1[tok * NC + c] + gv * lg + (1.f - gv) * sigmoidf_(lg);
    }
  }
}

extern "C" void kernel_launch(void* const* d_in, const int* in_sizes, int n_in,
                              void* d_out, int out_size, void* d_ws, size_t ws_size,
                              hipStream_t stream) {
  (void)in_sizes; (void)n_in; (void)out_size; (void)ws_size;
  const float* x      = (const float*)d_in[0];
  const float* n1g    = (const float*)d_in[1];
  const float* n1b    = (const float*)d_in[2];
  const float* qkv_w  = (const float*)d_in[3];
  const float* qkv_b  = (const float*)d_in[4];
  const float* proj_w = (const float*)d_in[5];
  const float* proj_b = (const float*)d_in[6];
  const float* n2g    = (const float*)d_in[7];
  const float* n2b    = (const float*)d_in[8];
  const float* fng    = (const float*)d_in[9];
  const float* fnb    = (const float*)d_in[10];
  const float* pin_w  = (const float*)d_in[11];
  const float* pin_b  = (const float*)d_in[12];
  const float* tm_inc = (const float*)d_in[13];
  const float* tm_out = (const float*)d_in[14];
  const float* gate   = (const float*)d_in[15];

  float* x1 = (float*)d_ws;                         // NTOK*96 f32
  u16* zb    = (u16*)(x1 + (size_t)NTOK * NC);      // NTOK*96 bf16
  u16* maskb = zb + (size_t)NTOK * NC;              // 128*768 bf16
  u16* pinwb = maskb + NCL_ * NLIT;                 // 384*96 bf16
  u16* tmoT  = pinwb + HID_ * NC;                   // 96*128 bf16
  u16* qkvwb = tmoT + NC * NCL_;                    // 288*96 bf16
  u16* projwb= qkvwb + 3 * NC * NC;                 // 96*96 bf16

  hipLaunchKernelGGL(k0_prep, dim3(384), dim3(256), 0, stream,
                     tm_inc, pin_w, tm_out, qkv_w, proj_w, maskb, pinwb, tmoT, qkvwb, projwb);
  hipLaunchKernelGGL(k2_attn, dim3(NWIN), dim3(256), 0, stream,
                     x, n1g, n1b, qkvwb, qkv_b, projwb, proj_b, x1);
  hipLaunchKernelGGL(k3_ln2, dim3(NTOK / 4), dim3(256), 0, stream, x1, n2g, n2b, fng, fnb, zb);
  hipLaunchKernelGGL(k4_ffn, dim3(NTOK / 16), dim3(256), 0, stream,
                     zb, x1, pinwb, pin_b, maskb, tmoT, gate, (float*)d_out);
}

// Round 7
// 237.747 us; speedup vs baseline: 3.6417x; 1.0778x over previous
//
#include <hip/hip_runtime.h>

// ---- problem constants (B,H0,W0,C)=(16,56,56,96), NH=3, WS=7, SS=3, HID=384, NCL=128 ----
#define NB 16
#define NHH 56
#define NWW 56
#define NC 96
#define NL (NHH*NWW)          // 3136
#define NTOK (NB*NL)          // 50176
#define WSZ 7
#define NT 49                 // tokens per window
#define SSH 3
#define NWIN 1024             // 16 * 8 * 8
#define HDIM 32
#define HID_ 384
#define NCL_ 128
#define NLIT 768
#define EPS_ 1e-6f

typedef unsigned short u16;
typedef unsigned int   u32;
typedef __attribute__((ext_vector_type(8))) short short8;   // 8 bf16 (4 VGPRs)
typedef __attribute__((ext_vector_type(4))) float f32x4;    // MFMA C/D

__device__ __forceinline__ float us2f(u16 u) {
  union { u32 u; float f; } x; x.u = ((u32)u) << 16; return x.f;
}
__device__ __forceinline__ u16 f2us(float f) {   // RNE float->bf16
  union { float f; u32 u; } x; x.f = f;
  u32 lsb = (x.u >> 16) & 1u;
  return (u16)((x.u + 0x7fffu + lsb) >> 16);
}
__device__ __forceinline__ float sigmoidf_(float x) { return 1.f / (1.f + __expf(-x)); }

// ---------------- K0: build bf16 constants ----------------
__global__ __launch_bounds__(256) void k0_prep(const float* __restrict__ tm_inc,
                                               const float* __restrict__ pin_w,
                                               const float* __restrict__ tm_out,
                                               const float* __restrict__ qkv_w,
                                               const float* __restrict__ proj_w,
                                               u16* __restrict__ maskb,
                                               u16* __restrict__ pinwb,
                                               u16* __restrict__ tmoT,
                                               u16* __restrict__ qkvwb,
                                               u16* __restrict__ projwb) {
  int idx = blockIdx.x * 256 + threadIdx.x;
  if (idx < NCL_ * NLIT)
    maskb[idx] = (tm_inc[idx] > 0.f) ? (u16)0x3F80 : (u16)0;
  if (idx < HID_ * NC)
    pinwb[idx] = f2us(pin_w[idx]);
  if (idx < NC * NCL_) {
    int c = idx / NCL_, k = idx - c * NCL_;
    tmoT[idx] = f2us(tm_out[(size_t)k * NC + c]);
  }
  if (idx < 3 * NC * NC)
    qkvwb[idx] = f2us(qkv_w[idx]);
  if (idx < NC * NC)
    projwb[idx] = f2us(proj_w[idx]);
}

// ---------------- K2: LN1 + window gather + MFMA attention + proj + residual scatter ----------------
// One block = one window. 4 waves; wave w owns query rows 16w..16w+15.
__global__ __launch_bounds__(256) void k2_attn(const float* __restrict__ x,
                                               const float* __restrict__ n1g,
                                               const float* __restrict__ n1b,
                                               const u16* __restrict__ qkvwb,
                                               const float* __restrict__ qkv_b,
                                               const u16* __restrict__ projwb,
                                               const float* __restrict__ proj_b,
                                               float* __restrict__ x1) {
  __shared__ __align__(16) u16 syb[64 * 104];
  __shared__ __align__(16) u16 sq [64 * 104];
  __shared__ __align__(16) u16 sk [64 * 104];
  __shared__ __align__(16) u16 svT[96 * 72];
  __shared__ __align__(16) u16 sp [4 * 16 * 72];
  const int tid  = threadIdx.x;
  const int wave = tid >> 6;
  const int lane = tid & 63;
  const int l16  = lane & 15;
  const int quad = lane >> 4;
  const int win  = blockIdx.x;
  const int t0   = wave * 16;
  const int bb = win >> 6, wl = win & 63;
  const int hbase = (wl >> 3) * WSZ, wbase = (wl & 7) * WSZ;

  // ---- LN1 head: 4 threads per token; gather from x with inverse global roll ----
  {
    const int t = tid >> 2, s = tid & 3;
    if (t < NT) {
      int hp = hbase + t / WSZ, wp = wbase + t % WSZ;
      int h = hp + SSH; if (h >= NHH) h -= NHH;
      int w = wp + SSH; if (w >= NWW) w -= NWW;
      const float* xp = x + ((size_t)bb * NL + (size_t)h * NWW + w) * NC;
      float4 v[6];
      float sum = 0.f;
      #pragma unroll
      for (int k = 0; k < 6; ++k) {
        v[k] = *reinterpret_cast<const float4*>(xp + s * 4 + k * 16);
        sum += v[k].x + v[k].y + v[k].z + v[k].w;
      }
      sum += __shfl_xor(sum, 1); sum += __shfl_xor(sum, 2);
      float mean = sum * (1.f / 96.f);
      float ssq = 0.f;
      #pragma unroll
      for (int k = 0; k < 6; ++k) {
        float d0 = v[k].x - mean, d1 = v[k].y - mean;
        float d2 = v[k].z - mean, d3 = v[k].w - mean;
        ssq += d0 * d0 + d1 * d1 + d2 * d2 + d3 * d3;
      }
      ssq += __shfl_xor(ssq, 1); ssq += __shfl_xor(ssq, 2);
      float rstd = rsqrtf(ssq * (1.f / 96.f) + 1e-5f);
      #pragma unroll
      for (int k = 0; k < 6; ++k) {
        int c = s * 4 + k * 16;
        const float4 g4 = *reinterpret_cast<const float4*>(n1g + c);
        const float4 b4 = *reinterpret_cast<const float4*>(n1b + c);
        syb[t * 104 + c + 0] = f2us((v[k].x - mean) * rstd * g4.x + b4.x);
        syb[t * 104 + c + 1] = f2us((v[k].y - mean) * rstd * g4.y + b4.y);
        syb[t * 104 + c + 2] = f2us((v[k].z - mean) * rstd * g4.z + b4.z);
        syb[t * 104 + c + 3] = f2us((v[k].w - mean) * rstd * g4.w + b4.w);
      }
    } else {
      #pragma unroll
      for (int k = 0; k < 6; ++k) {
        int c = s * 4 + k * 16;
        syb[t * 104 + c + 0] = 0; syb[t * 104 + c + 1] = 0;
        syb[t * 104 + c + 2] = 0; syb[t * 104 + c + 3] = 0;
      }
    }
  }
  __syncthreads();

  // ---- QKV: M=64, N=288 (18 tiles), K=96 (3 steps); depth-4 B-frag ring ----
  {
    short8 afr[3];
    #pragma unroll
    for (int ks = 0; ks < 3; ++ks)
      afr[ks] = *reinterpret_cast<const short8*>(&syb[(t0 + l16) * 104 + quad * 8 + ks * 32]);
    short8 rb[4][3];
    #pragma unroll
    for (int p = 0; p < 4; ++p)
      #pragma unroll
      for (int ks = 0; ks < 3; ++ks)
        rb[p][ks] = *reinterpret_cast<const short8*>(
            qkvwb + (size_t)(p * 16 + l16) * NC + quad * 8 + ks * 32);
    #pragma unroll
    for (int nt = 0; nt < 18; ++nt) {
      const int n0 = nt * 16;
      const float bias = qkv_b[n0 + l16];
      short8 b0 = rb[nt & 3][0], b1 = rb[nt & 3][1], b2 = rb[nt & 3][2];
      if (nt + 4 < 18) {
        #pragma unroll
        for (int ks = 0; ks < 3; ++ks)
          rb[nt & 3][ks] = *reinterpret_cast<const short8*>(
              qkvwb + (size_t)((nt + 4) * 16 + l16) * NC + quad * 8 + ks * 32);
      }
      f32x4 acc = {0.f, 0.f, 0.f, 0.f};
      acc = __builtin_amdgcn_mfma_f32_16x16x32_bf16(afr[0], b0, acc, 0, 0, 0);
      acc = __builtin_amdgcn_mfma_f32_16x16x32_bf16(afr[1], b1, acc, 0, 0, 0);
      acc = __builtin_amdgcn_mfma_f32_16x16x32_bf16(afr[2], b2, acc, 0, 0, 0);
      const int part = nt / 6;                 // 0=q 1=k 2=v
      const int oc = n0 - part * 96 + l16;
      if (part < 2) {
        u16* dst = (part == 0) ? sq : sk;
        #pragma unroll
        for (int r = 0; r < 4; ++r)
          dst[(t0 + quad * 4 + r) * 104 + oc] = f2us(acc[r] + bias);
      } else {
        #pragma unroll
        for (int r = 0; r < 4; ++r)
          svT[oc * 72 + (t0 + quad * 4 + r)] = f2us(acc[r] + bias);
      }
    }
  }
  __syncthreads();

  // ---- per head: scores -> in-register softmax -> PV (all wave-private) ----
  u16* spw = sp + wave * 16 * 72;
  const float sscale = 0.17677669529663687f;
  for (int h = 0; h < 3; ++h) {
    const int d0 = h * HDIM;
    short8 qf = *reinterpret_cast<const short8*>(&sq[(t0 + l16) * 104 + d0 + quad * 8]);
    f32x4 s[4];
    #pragma unroll
    for (int nt = 0; nt < 4; ++nt) {
      short8 kf = *reinterpret_cast<const short8*>(&sk[(nt * 16 + l16) * 104 + d0 + quad * 8]);
      f32x4 a = {0.f, 0.f, 0.f, 0.f};
      s[nt] = __builtin_amdgcn_mfma_f32_16x16x32_bf16(qf, kf, a, 0, 0, 0);
    }
    #pragma unroll
    for (int nt = 0; nt < 4; ++nt)
      #pragma unroll
      for (int r = 0; r < 4; ++r) s[nt][r] *= sscale;
    if (l16 >= 1) {                       // key col 48+l16 >= 49 -> mask
      #pragma unroll
      for (int r = 0; r < 4; ++r) s[3][r] = -1e30f;
    }
    #pragma unroll
    for (int r = 0; r < 4; ++r) {
      float m = fmaxf(fmaxf(s[0][r], s[1][r]), fmaxf(s[2][r], s[3][r]));
      #pragma unroll
      for (int off = 8; off > 0; off >>= 1) m = fmaxf(m, __shfl_xor(m, off, 16));
      float e0 = __expf(s[0][r] - m), e1 = __expf(s[1][r] - m);
      float e2 = __expf(s[2][r] - m), e3 = __expf(s[3][r] - m);
      float sum = e0 + e1 + e2 + e3;
      #pragma unroll
      for (int off = 8; off > 0; off >>= 1) sum += __shfl_xor(sum, off, 16);
      float inv = 1.f / sum;
      const int row = quad * 4 + r;
      spw[row * 72 +      l16] = f2us(e0 * inv);
      spw[row * 72 + 16 + l16] = f2us(e1 * inv);
      spw[row * 72 + 32 + l16] = f2us(e2 * inv);
      spw[row * 72 + 48 + l16] = f2us(e3 * inv);
    }
    short8 pa[2];
    pa[0] = *reinterpret_cast<const short8*>(&spw[l16 * 72 + quad * 8]);
    pa[1] = *reinterpret_cast<const short8*>(&spw[l16 * 72 + 32 + quad * 8]);
    #pragma unroll
    for (int nt = 0; nt < 2; ++nt) {
      const int c0 = d0 + nt * 16;
      f32x4 acc = {0.f, 0.f, 0.f, 0.f};
      #pragma unroll
      for (int ks = 0; ks < 2; ++ks) {
        short8 vb = *reinterpret_cast<const short8*>(&svT[(c0 + l16) * 72 + ks * 32 + quad * 8]);
        acc = __builtin_amdgcn_mfma_f32_16x16x32_bf16(pa[ks], vb, acc, 0, 0, 0);
      }
      #pragma unroll
      for (int r = 0; r < 4; ++r)
        syb[(t0 + quad * 4 + r) * 104 + c0 + l16] = f2us(acc[r]);
    }
  }

  // ---- proj: N=96 (6 tiles), K=96 (3 steps); prefetched residuals + depth-2 B ring ----
  {
    short8 aa[3];
    #pragma unroll
    for (int ks = 0; ks < 3; ++ks)
      aa[ks] = *reinterpret_cast<const short8*>(&syb[(t0 + l16) * 104 + quad * 8 + ks * 32]);

    size_t tokr[4]; bool tval[4];
    #pragma unroll
    for (int r = 0; r < 4; ++r) {
      const int t = t0 + quad * 4 + r;
      tval[r] = (t < NT);
      int rr = t / WSZ + SSH; if (rr >= WSZ) rr -= WSZ;
      int qq = t % WSZ + SSH; if (qq >= WSZ) qq -= WSZ;
      tokr[r] = (size_t)bb * NL + (size_t)(hbase + rr) * NWW + (wbase + qq);
    }
    float xv[6][4];
    #pragma unroll
    for (int nt = 0; nt < 6; ++nt)
      #pragma unroll
      for (int r = 0; r < 4; ++r)
        xv[nt][r] = tval[r] ? x[tokr[r] * NC + nt * 16 + l16] : 0.f;

    short8 pbr[2][3];
    #pragma unroll
    for (int ks = 0; ks < 3; ++ks)
      pbr[0][ks] = *reinterpret_cast<const short8*>(
          projwb + (size_t)l16 * NC + quad * 8 + ks * 32);
    #pragma unroll
    for (int nt = 0; nt < 6; ++nt) {
      const int n0 = nt * 16;
      const float pb = proj_b[n0 + l16];
      short8 b0 = pbr[nt & 1][0], b1 = pbr[nt & 1][1], b2 = pbr[nt & 1][2];
      if (nt + 1 < 6) {
        #pragma unroll
        for (int ks = 0; ks < 3; ++ks)
          pbr[(nt + 1) & 1][ks] = *reinterpret_cast<const short8*>(
              projwb + (size_t)((nt + 1) * 16 + l16) * NC + quad * 8 + ks * 32);
      }
      f32x4 acc = {0.f, 0.f, 0.f, 0.f};
      acc = __builtin_amdgcn_mfma_f32_16x16x32_bf16(aa[0], b0, acc, 0, 0, 0);
      acc = __builtin_amdgcn_mfma_f32_16x16x32_bf16(aa[1], b1, acc, 0, 0, 0);
      acc = __builtin_amdgcn_mfma_f32_16x16x32_bf16(aa[2], b2, acc, 0, 0, 0);
      #pragma unroll
      for (int r = 0; r < 4; ++r) {
        if (tval[r])
          x1[tokr[r] * NC + n0 + l16] = xv[nt][r] + acc[r] + pb;
      }
    }
  }
}

// ---------------- K3: z = bf16( LN(LN(x1)) ) — 16 lanes/token, two-pass ----------------
__global__ __launch_bounds__(256) void k3_ln2(const float* __restrict__ x1,
                                              const float* __restrict__ g2,
                                              const float* __restrict__ b2,
                                              const float* __restrict__ gf,
                                              const float* __restrict__ bf,
                                              u16* __restrict__ zb) {
  const int tid = threadIdx.x;
  const int t = tid >> 4, s = tid & 15;
  const size_t token = (size_t)blockIdx.x * 16 + t;
  const float* xp = x1 + token * NC;
  float2 v[3];
  float sum = 0.f;
  #pragma unroll
  for (int k = 0; k < 3; ++k) {
    v[k] = *reinterpret_cast<const float2*>(xp + s * 2 + k * 32);
    sum += v[k].x + v[k].y;
  }
  #pragma unroll
  for (int off = 8; off > 0; off >>= 1) sum += __shfl_xor(sum, off, 16);
  const float mean = sum * (1.f / 96.f);
  float ssq = 0.f;
  #pragma unroll
  for (int k = 0; k < 3; ++k) {
    float d0 = v[k].x - mean, d1 = v[k].y - mean;
    ssq += d0 * d0 + d1 * d1;
  }
  #pragma unroll
  for (int off = 8; off > 0; off >>= 1) ssq += __shfl_xor(ssq, off, 16);
  const float rstd = rsqrtf(ssq * (1.f / 96.f) + 1e-5f);
  float tv[6];
  float sum2 = 0.f;
  #pragma unroll
  for (int k = 0; k < 3; ++k) {
    const int c = s * 2 + k * 32;
    const float2 gg = *reinterpret_cast<const float2*>(g2 + c);
    const float2 bb = *reinterpret_cast<const float2*>(b2 + c);
    tv[2 * k]     = (v[k].x - mean) * rstd * gg.x + bb.x;
    tv[2 * k + 1] = (v[k].y - mean) * rstd * gg.y + bb.y;
    sum2 += tv[2 * k] + tv[2 * k + 1];
  }
  #pragma unroll
  for (int off = 8; off > 0; off >>= 1) sum2 += __shfl_xor(sum2, off, 16);
  const float mean2 = sum2 * (1.f / 96.f);
  float ssq2 = 0.f;
  #pragma unroll
  for (int k = 0; k < 3; ++k) {
    float d0 = tv[2 * k] - mean2, d1 = tv[2 * k + 1] - mean2;
    ssq2 += d0 * d0 + d1 * d1;
  }
  #pragma unroll
  for (int off = 8; off > 0; off >>= 1) ssq2 += __shfl_xor(ssq2, off, 16);
  const float rstd2 = rsqrtf(ssq2 * (1.f / 96.f) + 1e-5f);
  u16* zp = zb + token * NC;
  #pragma unroll
  for (int k = 0; k < 3; ++k) {
    const int c = s * 2 + k * 32;
    const float2 gg = *reinterpret_cast<const float2*>(gf + c);
    const float2 bb = *reinterpret_cast<const float2*>(bf + c);
    u16 lo = f2us((tv[2 * k]     - mean2) * rstd2 * gg.x + bb.x);
    u16 hi = f2us((tv[2 * k + 1] - mean2) * rstd2 * gg.y + bb.y);
    *reinterpret_cast<u32*>(zp + c) = (u32)lo | ((u32)hi << 16);
  }
}

// ---------------- K4: TM-FFN via MFMA, software-pipelined loads ----------------
__global__ __launch_bounds__(256) void k4_ffn(const u16* __restrict__ zb,
                                              const float* __restrict__ x1,
                                              const u16* __restrict__ pinwb,
                                              const float* __restrict__ pin_b,
                                              const u16* __restrict__ maskb,
                                              const u16* __restrict__ tmoT,
                                              const float* __restrict__ gate,
                                              float* __restrict__ out) {
  __shared__ __align__(16) u16 lit[16 * 776];       // bf16 log-literals [t][j]
  __shared__ __align__(16) u16 claT[16 * 136];      // bf16 clauses [t][k]
  const int tid  = threadIdx.x;
  const int wave = tid >> 6;
  const int lane = tid & 63;
  const int l16  = lane & 15;
  const int quad = lane >> 4;
  const size_t tok0 = (size_t)blockIdx.x * 16;

  // prefetch epilogue residuals + gate + biases + A-frags up-front
  float xr[2][4];
  #pragma unroll
  for (int ii = 0; ii < 2; ++ii) {
    const int nt = wave + ii * 4;
    if (nt < 6) {
      #pragma unroll
      for (int r = 0; r < 4; ++r)
        xr[ii][r] = x1[(tok0 + quad * 4 + r) * NC + nt * 16 + l16];
    }
  }
  const float gv = sigmoidf_(gate[0]);

  short8 a3[3];
  #pragma unroll
  for (int ks = 0; ks < 3; ++ks)
    a3[ks] = *reinterpret_cast<const short8*>(zb + (tok0 + l16) * NC + quad * 8 + ks * 32);

  float pbias[6];
  #pragma unroll
  for (int i = 0; i < 6; ++i) pbias[i] = pin_b[(wave * 6 + i) * 16 + l16];

  // ---- pin gemm: wave w -> tiles [6w,6w+6); depth-2 B ring, loads hidden under transcendentals ----
  short8 pb[2][3];
  #pragma unroll
  for (int ks = 0; ks < 3; ++ks)
    pb[0][ks] = *reinterpret_cast<const short8*>(
        pinwb + (size_t)(wave * 6 * 16 + l16) * NC + quad * 8 + ks * 32);
  #pragma unroll
  for (int i = 0; i < 6; ++i) {
    short8 b0 = pb[i & 1][0], b1 = pb[i & 1][1], b2 = pb[i & 1][2];
    if (i + 1 < 6) {
      const int n1 = (wave * 6 + i + 1) * 16;
      #pragma unroll
      for (int ks = 0; ks < 3; ++ks)
        pb[(i + 1) & 1][ks] = *reinterpret_cast<const short8*>(
            pinwb + (size_t)(n1 + l16) * NC + quad * 8 + ks * 32);
    }
    f32x4 acc = {0.f, 0.f, 0.f, 0.f};
    acc = __builtin_amdgcn_mfma_f32_16x16x32_bf16(a3[0], b0, acc, 0, 0, 0);
    acc = __builtin_amdgcn_mfma_f32_16x16x32_bf16(a3[1], b1, acc, 0, 0, 0);
    acc = __builtin_amdgcn_mfma_f32_16x16x32_bf16(a3[2], b2, acc, 0, 0, 0);
    const int o = (wave * 6 + i) * 16 + l16;
    const float pbv = pbias[i];
    #pragma unroll
    for (int r = 0; r < 4; ++r) {
      const int t = quad * 4 + r;
      float y = sigmoidf_(acc[r] + pbv);
      lit[t * 776 + o]       = f2us(__logf(fmaxf(y, EPS_)));
      lit[t * 776 + 384 + o] = f2us(__logf(fmaxf(1.f - y, EPS_)));
    }
  }
  __syncthreads();

  // ---- clause gemm: wave w -> clause tiles {2w,2w+1}; depth-4 B ring ----
  {
    const int ct0 = wave * 2;
    const u16* bp0 = maskb + (size_t)((ct0 + 0) * 16 + l16) * NLIT + quad * 8;
    const u16* bp1 = maskb + (size_t)((ct0 + 1) * 16 + l16) * NLIT + quad * 8;
    short8 rb0[4], rb1[4];
    #pragma unroll
    for (int p = 0; p < 4; ++p) {
      rb0[p] = *reinterpret_cast<const short8*>(bp0 + p * 32);
      rb1[p] = *reinterpret_cast<const short8*>(bp1 + p * 32);
    }
    f32x4 c0 = {0.f, 0.f, 0.f, 0.f}, c1 = {0.f, 0.f, 0.f, 0.f};
    #pragma unroll
    for (int ks = 0; ks < 24; ++ks) {
      short8 a = *reinterpret_cast<const short8*>(&lit[l16 * 776 + ks * 32 + quad * 8]);
      short8 b0 = rb0[ks & 3], b1 = rb1[ks & 3];
      if (ks + 4 < 24) {
        rb0[ks & 3] = *reinterpret_cast<const short8*>(bp0 + (ks + 4) * 32);
        rb1[ks & 3] = *reinterpret_cast<const short8*>(bp1 + (ks + 4) * 32);
      }
      c0 = __builtin_amdgcn_mfma_f32_16x16x32_bf16(a, b0, c0, 0, 0, 0);
      c1 = __builtin_amdgcn_mfma_f32_16x16x32_bf16(a, b1, c1, 0, 0, 0);
    }
    #pragma unroll
    for (int r = 0; r < 4; ++r) {
      const int t = quad * 4 + r;
      claT[t * 136 + (ct0 + 0) * 16 + l16] = f2us(__expf(c0[r]));
      claT[t * 136 + (ct0 + 1) * 16 + l16] = f2us(__expf(c1[r]));
    }
  }
  __syncthreads();

  // ---- logits = cla @ tm_out; fused blend epilogue (residuals prefetched) ----
  #pragma unroll
  for (int ii = 0; ii < 2; ++ii) {
    const int nt = wave + ii * 4;
    if (nt < 6) {
      f32x4 acc = {0.f, 0.f, 0.f, 0.f};
      #pragma unroll
      for (int ks = 0; ks < 4; ++ks) {
        const int k0 = ks * 32 + quad * 8;
        short8 a = *reinterpret_cast<const short8*>(&claT[l16 * 136 + k0]);
        short8 b = *reinterpret_cast<const short8*>(
            tmoT + (size_t)(nt * 16 + l16) * NCL_ + k0);
        acc = __builtin_amdgcn_mfma_f32_16x16x32_bf16(a, b, acc, 0, 0, 0);
      }
      const int c = nt * 16 + l16;
      #pragma unroll
      for (int r = 0; r < 4; ++r) {
        const size_t tok = tok0 + quad * 4 + r;
        float lg = acc[r];
        out[tok * NC + c] = xr[ii][r] + gv * lg + (1.f - gv) * sigmoidf_(lg);
      }
    }
  }
}

extern "C" void kernel_launch(void* const* d_in, const int* in_sizes, int n_in,
                              void* d_out, int out_size, void* d_ws, size_t ws_size,
                              hipStream_t stream) {
  (void)in_sizes; (void)n_in; (void)out_size; (void)ws_size;
  const float* x      = (const float*)d_in[0];
  const float* n1g    = (const float*)d_in[1];
  const float* n1b    = (const float*)d_in[2];
  const float* qkv_w  = (const float*)d_in[3];
  const float* qkv_b  = (const float*)d_in[4];
  const float* proj_w = (const float*)d_in[5];
  const float* proj_b = (const float*)d_in[6];
  const float* n2g    = (const float*)d_in[7];
  const float* n2b    = (const float*)d_in[8];
  const float* fng    = (const float*)d_in[9];
  const float* fnb    = (const float*)d_in[10];
  const float* pin_w  = (const float*)d_in[11];
  const float* pin_b  = (const float*)d_in[12];
  const float* tm_inc = (const float*)d_in[13];
  const float* tm_out = (const float*)d_in[14];
  const float* gate   = (const float*)d_in[15];

  float* x1 = (float*)d_ws;                         // NTOK*96 f32
  u16* zb    = (u16*)(x1 + (size_t)NTOK * NC);      // NTOK*96 bf16
  u16* maskb = zb + (size_t)NTOK * NC;              // 128*768 bf16
  u16* pinwb = maskb + NCL_ * NLIT;                 // 384*96 bf16
  u16* tmoT  = pinwb + HID_ * NC;                   // 96*128 bf16
  u16* qkvwb = tmoT + NC * NCL_;                    // 288*96 bf16
  u16* projwb= qkvwb + 3 * NC * NC;                 // 96*96 bf16

  hipLaunchKernelGGL(k0_prep, dim3(384), dim3(256), 0, stream,
                     tm_inc, pin_w, tm_out, qkv_w, proj_w, maskb, pinwb, tmoT, qkvwb, projwb);
  hipLaunchKernelGGL(k2_attn, dim3(NWIN), dim3(256), 0, stream,
                     x, n1g, n1b, qkvwb, qkv_b, projwb, proj_b, x1);
  hipLaunchKernelGGL(k3_ln2, dim3(NTOK / 16), dim3(256), 0, stream, x1, n2g, n2b, fng, fnb, zb);
  hipLaunchKernelGGL(k4_ffn, dim3(NTOK / 16), dim3(256), 0, stream,
                     zb, x1, pinwb, pin_b, maskb, tmoT, gate, (float*)d_out);
}

// Round 8
// 206.146 us; speedup vs baseline: 4.1999x; 1.1533x over previous
//
#include <hip/hip_runtime.h>

// ---- problem constants (B,H0,W0,C)=(16,56,56,96), NH=3, WS=7, SS=3, HID=384, NCL=128 ----
#define NB 16
#define NHH 56
#define NWW 56
#define NC 96
#define NL (NHH*NWW)          // 3136
#define NTOK (NB*NL)          // 50176
#define WSZ 7
#define NT 49                 // tokens per window
#define SSH 3
#define NWIN 1024             // 16 * 8 * 8
#define HDIM 32
#define HID_ 384
#define NCL_ 128
#define NLIT 768
#define EPS_ 1e-6f

typedef unsigned short u16;
typedef unsigned int   u32;
typedef __attribute__((ext_vector_type(8))) short short8;   // 8 bf16 (4 VGPRs)
typedef __attribute__((ext_vector_type(4))) float f32x4;    // MFMA C/D

__device__ __forceinline__ float us2f(u16 u) {
  union { u32 u; float f; } x; x.u = ((u32)u) << 16; return x.f;
}
__device__ __forceinline__ u16 f2us(float f) {   // RNE float->bf16
  union { float f; u32 u; } x; x.f = f;
  u32 lsb = (x.u >> 16) & 1u;
  return (u16)((x.u + 0x7fffu + lsb) >> 16);
}
__device__ __forceinline__ float sigmoidf_(float x) { return 1.f / (1.f + __expf(-x)); }

// ---------------- K0: build bf16 constants ----------------
__global__ __launch_bounds__(256) void k0_prep(const float* __restrict__ tm_inc,
                                               const float* __restrict__ pin_w,
                                               const float* __restrict__ tm_out,
                                               const float* __restrict__ qkv_w,
                                               const float* __restrict__ proj_w,
                                               u16* __restrict__ maskb,
                                               u16* __restrict__ pinwb,
                                               u16* __restrict__ tmoT,
                                               u16* __restrict__ qkvwb,
                                               u16* __restrict__ projwb) {
  int idx = blockIdx.x * 256 + threadIdx.x;
  if (idx < NCL_ * NLIT)
    maskb[idx] = (tm_inc[idx] > 0.f) ? (u16)0x3F80 : (u16)0;
  if (idx < HID_ * NC)
    pinwb[idx] = f2us(pin_w[idx]);
  if (idx < NC * NCL_) {
    int c = idx / NCL_, k = idx - c * NCL_;
    tmoT[idx] = f2us(tm_out[(size_t)k * NC + c]);
  }
  if (idx < 3 * NC * NC)
    qkvwb[idx] = f2us(qkv_w[idx]);
  if (idx < NC * NC)
    projwb[idx] = f2us(proj_w[idx]);
}

// ---------------- K2: LN1 + window gather + MFMA attention + proj + residual scatter ----------------
// One block = one window. 4 waves; wave w owns query rows 16w..16w+15. (unchanged from round 7)
__global__ __launch_bounds__(256) void k2_attn(const float* __restrict__ x,
                                               const float* __restrict__ n1g,
                                               const float* __restrict__ n1b,
                                               const u16* __restrict__ qkvwb,
                                               const float* __restrict__ qkv_b,
                                               const u16* __restrict__ projwb,
                                               const float* __restrict__ proj_b,
                                               float* __restrict__ x1) {
  __shared__ __align__(16) u16 syb[64 * 104];
  __shared__ __align__(16) u16 sq [64 * 104];
  __shared__ __align__(16) u16 sk [64 * 104];
  __shared__ __align__(16) u16 svT[96 * 72];
  __shared__ __align__(16) u16 sp [4 * 16 * 72];
  const int tid  = threadIdx.x;
  const int wave = tid >> 6;
  const int lane = tid & 63;
  const int l16  = lane & 15;
  const int quad = lane >> 4;
  const int win  = blockIdx.x;
  const int t0   = wave * 16;
  const int bb = win >> 6, wl = win & 63;
  const int hbase = (wl >> 3) * WSZ, wbase = (wl & 7) * WSZ;

  // ---- LN1 head: 4 threads per token; gather from x with inverse global roll ----
  {
    const int t = tid >> 2, s = tid & 3;
    if (t < NT) {
      int hp = hbase + t / WSZ, wp = wbase + t % WSZ;
      int h = hp + SSH; if (h >= NHH) h -= NHH;
      int w = wp + SSH; if (w >= NWW) w -= NWW;
      const float* xp = x + ((size_t)bb * NL + (size_t)h * NWW + w) * NC;
      float4 v[6];
      float sum = 0.f;
      #pragma unroll
      for (int k = 0; k < 6; ++k) {
        v[k] = *reinterpret_cast<const float4*>(xp + s * 4 + k * 16);
        sum += v[k].x + v[k].y + v[k].z + v[k].w;
      }
      sum += __shfl_xor(sum, 1); sum += __shfl_xor(sum, 2);
      float mean = sum * (1.f / 96.f);
      float ssq = 0.f;
      #pragma unroll
      for (int k = 0; k < 6; ++k) {
        float d0 = v[k].x - mean, d1 = v[k].y - mean;
        float d2 = v[k].z - mean, d3 = v[k].w - mean;
        ssq += d0 * d0 + d1 * d1 + d2 * d2 + d3 * d3;
      }
      ssq += __shfl_xor(ssq, 1); ssq += __shfl_xor(ssq, 2);
      float rstd = rsqrtf(ssq * (1.f / 96.f) + 1e-5f);
      #pragma unroll
      for (int k = 0; k < 6; ++k) {
        int c = s * 4 + k * 16;
        const float4 g4 = *reinterpret_cast<const float4*>(n1g + c);
        const float4 b4 = *reinterpret_cast<const float4*>(n1b + c);
        syb[t * 104 + c + 0] = f2us((v[k].x - mean) * rstd * g4.x + b4.x);
        syb[t * 104 + c + 1] = f2us((v[k].y - mean) * rstd * g4.y + b4.y);
        syb[t * 104 + c + 2] = f2us((v[k].z - mean) * rstd * g4.z + b4.z);
        syb[t * 104 + c + 3] = f2us((v[k].w - mean) * rstd * g4.w + b4.w);
      }
    } else {
      #pragma unroll
      for (int k = 0; k < 6; ++k) {
        int c = s * 4 + k * 16;
        syb[t * 104 + c + 0] = 0; syb[t * 104 + c + 1] = 0;
        syb[t * 104 + c + 2] = 0; syb[t * 104 + c + 3] = 0;
      }
    }
  }
  __syncthreads();

  // ---- QKV: M=64, N=288 (18 tiles), K=96 (3 steps); depth-4 B-frag ring ----
  {
    short8 afr[3];
    #pragma unroll
    for (int ks = 0; ks < 3; ++ks)
      afr[ks] = *reinterpret_cast<const short8*>(&syb[(t0 + l16) * 104 + quad * 8 + ks * 32]);
    short8 rb[4][3];
    #pragma unroll
    for (int p = 0; p < 4; ++p)
      #pragma unroll
      for (int ks = 0; ks < 3; ++ks)
        rb[p][ks] = *reinterpret_cast<const short8*>(
            qkvwb + (size_t)(p * 16 + l16) * NC + quad * 8 + ks * 32);
    #pragma unroll
    for (int nt = 0; nt < 18; ++nt) {
      const int n0 = nt * 16;
      const float bias = qkv_b[n0 + l16];
      short8 b0 = rb[nt & 3][0], b1 = rb[nt & 3][1], b2 = rb[nt & 3][2];
      if (nt + 4 < 18) {
        #pragma unroll
        for (int ks = 0; ks < 3; ++ks)
          rb[nt & 3][ks] = *reinterpret_cast<const short8*>(
              qkvwb + (size_t)((nt + 4) * 16 + l16) * NC + quad * 8 + ks * 32);
      }
      f32x4 acc = {0.f, 0.f, 0.f, 0.f};
      acc = __builtin_amdgcn_mfma_f32_16x16x32_bf16(afr[0], b0, acc, 0, 0, 0);
      acc = __builtin_amdgcn_mfma_f32_16x16x32_bf16(afr[1], b1, acc, 0, 0, 0);
      acc = __builtin_amdgcn_mfma_f32_16x16x32_bf16(afr[2], b2, acc, 0, 0, 0);
      const int part = nt / 6;                 // 0=q 1=k 2=v
      const int oc = n0 - part * 96 + l16;
      if (part < 2) {
        u16* dst = (part == 0) ? sq : sk;
        #pragma unroll
        for (int r = 0; r < 4; ++r)
          dst[(t0 + quad * 4 + r) * 104 + oc] = f2us(acc[r] + bias);
      } else {
        #pragma unroll
        for (int r = 0; r < 4; ++r)
          svT[oc * 72 + (t0 + quad * 4 + r)] = f2us(acc[r] + bias);
      }
    }
  }
  __syncthreads();

  // ---- per head: scores -> in-register softmax -> PV (all wave-private) ----
  u16* spw = sp + wave * 16 * 72;
  const float sscale = 0.17677669529663687f;
  for (int h = 0; h < 3; ++h) {
    const int d0 = h * HDIM;
    short8 qf = *reinterpret_cast<const short8*>(&sq[(t0 + l16) * 104 + d0 + quad * 8]);
    f32x4 s[4];
    #pragma unroll
    for (int nt = 0; nt < 4; ++nt) {
      short8 kf = *reinterpret_cast<const short8*>(&sk[(nt * 16 + l16) * 104 + d0 + quad * 8]);
      f32x4 a = {0.f, 0.f, 0.f, 0.f};
      s[nt] = __builtin_amdgcn_mfma_f32_16x16x32_bf16(qf, kf, a, 0, 0, 0);
    }
    #pragma unroll
    for (int nt = 0; nt < 4; ++nt)
      #pragma unroll
      for (int r = 0; r < 4; ++r) s[nt][r] *= sscale;
    if (l16 >= 1) {                       // key col 48+l16 >= 49 -> mask
      #pragma unroll
      for (int r = 0; r < 4; ++r) s[3][r] = -1e30f;
    }
    #pragma unroll
    for (int r = 0; r < 4; ++r) {
      float m = fmaxf(fmaxf(s[0][r], s[1][r]), fmaxf(s[2][r], s[3][r]));
      #pragma unroll
      for (int off = 8; off > 0; off >>= 1) m = fmaxf(m, __shfl_xor(m, off, 16));
      float e0 = __expf(s[0][r] - m), e1 = __expf(s[1][r] - m);
      float e2 = __expf(s[2][r] - m), e3 = __expf(s[3][r] - m);
      float sum = e0 + e1 + e2 + e3;
      #pragma unroll
      for (int off = 8; off > 0; off >>= 1) sum += __shfl_xor(sum, off, 16);
      float inv = 1.f / sum;
      const int row = quad * 4 + r;
      spw[row * 72 +      l16] = f2us(e0 * inv);
      spw[row * 72 + 16 + l16] = f2us(e1 * inv);
      spw[row * 72 + 32 + l16] = f2us(e2 * inv);
      spw[row * 72 + 48 + l16] = f2us(e3 * inv);
    }
    short8 pa[2];
    pa[0] = *reinterpret_cast<const short8*>(&spw[l16 * 72 + quad * 8]);
    pa[1] = *reinterpret_cast<const short8*>(&spw[l16 * 72 + 32 + quad * 8]);
    #pragma unroll
    for (int nt = 0; nt < 2; ++nt) {
      const int c0 = d0 + nt * 16;
      f32x4 acc = {0.f, 0.f, 0.f, 0.f};
      #pragma unroll
      for (int ks = 0; ks < 2; ++ks) {
        short8 vb = *reinterpret_cast<const short8*>(&svT[(c0 + l16) * 72 + ks * 32 + quad * 8]);
        acc = __builtin_amdgcn_mfma_f32_16x16x32_bf16(pa[ks], vb, acc, 0, 0, 0);
      }
      #pragma unroll
      for (int r = 0; r < 4; ++r)
        syb[(t0 + quad * 4 + r) * 104 + c0 + l16] = f2us(acc[r]);
    }
  }

  // ---- proj: N=96 (6 tiles), K=96 (3 steps); prefetched residuals + depth-2 B ring ----
  {
    short8 aa[3];
    #pragma unroll
    for (int ks = 0; ks < 3; ++ks)
      aa[ks] = *reinterpret_cast<const short8*>(&syb[(t0 + l16) * 104 + quad * 8 + ks * 32]);

    size_t tokr[4]; bool tval[4];
    #pragma unroll
    for (int r = 0; r < 4; ++r) {
      const int t = t0 + quad * 4 + r;
      tval[r] = (t < NT);
      int rr = t / WSZ + SSH; if (rr >= WSZ) rr -= WSZ;
      int qq = t % WSZ + SSH; if (qq >= WSZ) qq -= WSZ;
      tokr[r] = (size_t)bb * NL + (size_t)(hbase + rr) * NWW + (wbase + qq);
    }
    float xv[6][4];
    #pragma unroll
    for (int nt = 0; nt < 6; ++nt)
      #pragma unroll
      for (int r = 0; r < 4; ++r)
        xv[nt][r] = tval[r] ? x[tokr[r] * NC + nt * 16 + l16] : 0.f;

    short8 pbr[2][3];
    #pragma unroll
    for (int ks = 0; ks < 3; ++ks)
      pbr[0][ks] = *reinterpret_cast<const short8*>(
          projwb + (size_t)l16 * NC + quad * 8 + ks * 32);
    #pragma unroll
    for (int nt = 0; nt < 6; ++nt) {
      const int n0 = nt * 16;
      const float pb = proj_b[n0 + l16];
      short8 b0 = pbr[nt & 1][0], b1 = pbr[nt & 1][1], b2 = pbr[nt & 1][2];
      if (nt + 1 < 6) {
        #pragma unroll
        for (int ks = 0; ks < 3; ++ks)
          pbr[(nt + 1) & 1][ks] = *reinterpret_cast<const short8*>(
              projwb + (size_t)((nt + 1) * 16 + l16) * NC + quad * 8 + ks * 32);
      }
      f32x4 acc = {0.f, 0.f, 0.f, 0.f};
      acc = __builtin_amdgcn_mfma_f32_16x16x32_bf16(aa[0], b0, acc, 0, 0, 0);
      acc = __builtin_amdgcn_mfma_f32_16x16x32_bf16(aa[1], b1, acc, 0, 0, 0);
      acc = __builtin_amdgcn_mfma_f32_16x16x32_bf16(aa[2], b2, acc, 0, 0, 0);
      #pragma unroll
      for (int r = 0; r < 4; ++r) {
        if (tval[r])
          x1[tokr[r] * NC + n0 + l16] = xv[nt][r] + acc[r] + pb;
      }
    }
  }
}

// ---------------- K4: double-LN + TM-FFN via MFMA; 32 tokens/block (2 M-tiles/wave) ----------------
// LDS: szb 6656 + lit 49664 + claT 8704 + sx1 12800 = 77,824 B -> 2 blocks/CU.
__global__ __launch_bounds__(256) void k4_ffn(const float* __restrict__ x1,
                                              const float* __restrict__ g2,
                                              const float* __restrict__ b2,
                                              const float* __restrict__ gf,
                                              const float* __restrict__ bf,
                                              const u16* __restrict__ pinwb,
                                              const float* __restrict__ pin_b,
                                              const u16* __restrict__ maskb,
                                              const u16* __restrict__ tmoT,
                                              const float* __restrict__ gate,
                                              float* __restrict__ out) {
  __shared__ __align__(16) u16 szb[32 * 104];       // bf16 double-LN'd z
  __shared__ __align__(16) u16 lit[32 * 776];       // bf16 log-literals [t][j]
  __shared__ __align__(16) u16 claT[32 * 136];      // bf16 clauses [t][k]
  __shared__ __align__(16) float sx1[32 * 100];     // f32 x1 rows (epilogue residual)
  const int tid  = threadIdx.x;
  const int wave = tid >> 6;
  const int lane = tid & 63;
  const int l16  = lane & 15;
  const int quad = lane >> 4;
  const size_t tok0 = (size_t)blockIdx.x * 32;

  // ---- LN(LN(x1)) head: 8 lanes per token, 12 channels each (float4 x 3) ----
  {
    const int t = tid >> 3, s = tid & 7;
    const float* xp = x1 + (tok0 + t) * NC;
    float4 v[3];
    float sum = 0.f;
    #pragma unroll
    for (int k = 0; k < 3; ++k) {
      const int c = s * 4 + k * 32;
      v[k] = *reinterpret_cast<const float4*>(xp + c);
      sum += v[k].x + v[k].y + v[k].z + v[k].w;
      *reinterpret_cast<float4*>(&sx1[t * 100 + c]) = v[k];
    }
    sum += __shfl_xor(sum, 1, 8); sum += __shfl_xor(sum, 2, 8); sum += __shfl_xor(sum, 4, 8);
    const float mean = sum * (1.f / 96.f);
    float ssq = 0.f;
    #pragma unroll
    for (int k = 0; k < 3; ++k) {
      float d0 = v[k].x - mean, d1 = v[k].y - mean;
      float d2 = v[k].z - mean, d3 = v[k].w - mean;
      ssq += d0 * d0 + d1 * d1 + d2 * d2 + d3 * d3;
    }
    ssq += __shfl_xor(ssq, 1, 8); ssq += __shfl_xor(ssq, 2, 8); ssq += __shfl_xor(ssq, 4, 8);
    const float rstd = rsqrtf(ssq * (1.f / 96.f) + 1e-5f);
    float tv[12];
    float sum2 = 0.f;
    #pragma unroll
    for (int k = 0; k < 3; ++k) {
      const int c = s * 4 + k * 32;
      const float4 gg = *reinterpret_cast<const float4*>(g2 + c);
      const float4 bb = *reinterpret_cast<const float4*>(b2 + c);
      tv[4 * k + 0] = (v[k].x - mean) * rstd * gg.x + bb.x;
      tv[4 * k + 1] = (v[k].y - mean) * rstd * gg.y + bb.y;
      tv[4 * k + 2] = (v[k].z - mean) * rstd * gg.z + bb.z;
      tv[4 * k + 3] = (v[k].w - mean) * rstd * gg.w + bb.w;
      sum2 += tv[4 * k] + tv[4 * k + 1] + tv[4 * k + 2] + tv[4 * k + 3];
    }
    sum2 += __shfl_xor(sum2, 1, 8); sum2 += __shfl_xor(sum2, 2, 8); sum2 += __shfl_xor(sum2, 4, 8);
    const float mean2 = sum2 * (1.f / 96.f);
    float ssq2 = 0.f;
    #pragma unroll
    for (int k = 0; k < 12; ++k) {
      float d = tv[k] - mean2;
      ssq2 += d * d;
    }
    ssq2 += __shfl_xor(ssq2, 1, 8); ssq2 += __shfl_xor(ssq2, 2, 8); ssq2 += __shfl_xor(ssq2, 4, 8);
    const float rstd2 = rsqrtf(ssq2 * (1.f / 96.f) + 1e-5f);
    #pragma unroll
    for (int k = 0; k < 3; ++k) {
      const int c = s * 4 + k * 32;
      const float4 gg = *reinterpret_cast<const float4*>(gf + c);
      const float4 bb = *reinterpret_cast<const float4*>(bf + c);
      u16 z0 = f2us((tv[4 * k + 0] - mean2) * rstd2 * gg.x + bb.x);
      u16 z1 = f2us((tv[4 * k + 1] - mean2) * rstd2 * gg.y + bb.y);
      u16 z2 = f2us((tv[4 * k + 2] - mean2) * rstd2 * gg.z + bb.z);
      u16 z3 = f2us((tv[4 * k + 3] - mean2) * rstd2 * gg.w + bb.w);
      *reinterpret_cast<u32*>(&szb[t * 104 + c])     = (u32)z0 | ((u32)z1 << 16);
      *reinterpret_cast<u32*>(&szb[t * 104 + c + 2]) = (u32)z2 | ((u32)z3 << 16);
    }
  }
  __syncthreads();

  const float gv = sigmoidf_(gate[0]);

  // A-frags for pin: 2 M-tiles x 3 k-steps
  short8 a_pin[2][3];
  #pragma unroll
  for (int mt = 0; mt < 2; ++mt)
    #pragma unroll
    for (int ks = 0; ks < 3; ++ks)
      a_pin[mt][ks] = *reinterpret_cast<const short8*>(
          &szb[(mt * 16 + l16) * 104 + quad * 8 + ks * 32]);

  // ---- pin gemm: wave w -> N-tiles [6w,6w+6); depth-2 B ring; 2 MFMA per B-frag ----
  {
    float pbias[6];
    #pragma unroll
    for (int i = 0; i < 6; ++i) pbias[i] = pin_b[(wave * 6 + i) * 16 + l16];
    short8 pb[2][3];
    #pragma unroll
    for (int ks = 0; ks < 3; ++ks)
      pb[0][ks] = *reinterpret_cast<const short8*>(
          pinwb + (size_t)(wave * 6 * 16 + l16) * NC + quad * 8 + ks * 32);
    #pragma unroll
    for (int i = 0; i < 6; ++i) {
      short8 b0 = pb[i & 1][0], b1 = pb[i & 1][1], b2 = pb[i & 1][2];
      if (i + 1 < 6) {
        const int n1 = (wave * 6 + i + 1) * 16;
        #pragma unroll
        for (int ks = 0; ks < 3; ++ks)
          pb[(i + 1) & 1][ks] = *reinterpret_cast<const short8*>(
              pinwb + (size_t)(n1 + l16) * NC + quad * 8 + ks * 32);
      }
      f32x4 acc0 = {0.f, 0.f, 0.f, 0.f}, acc1 = {0.f, 0.f, 0.f, 0.f};
      acc0 = __builtin_amdgcn_mfma_f32_16x16x32_bf16(a_pin[0][0], b0, acc0, 0, 0, 0);
      acc1 = __builtin_amdgcn_mfma_f32_16x16x32_bf16(a_pin[1][0], b0, acc1, 0, 0, 0);
      acc0 = __builtin_amdgcn_mfma_f32_16x16x32_bf16(a_pin[0][1], b1, acc0, 0, 0, 0);
      acc1 = __builtin_amdgcn_mfma_f32_16x16x32_bf16(a_pin[1][1], b1, acc1, 0, 0, 0);
      acc0 = __builtin_amdgcn_mfma_f32_16x16x32_bf16(a_pin[0][2], b2, acc0, 0, 0, 0);
      acc1 = __builtin_amdgcn_mfma_f32_16x16x32_bf16(a_pin[1][2], b2, acc1, 0, 0, 0);
      const int o = (wave * 6 + i) * 16 + l16;
      const float pbv = pbias[i];
      #pragma unroll
      for (int r = 0; r < 4; ++r) {
        float y0 = sigmoidf_(acc0[r] + pbv);
        float y1 = sigmoidf_(acc1[r] + pbv);
        const int ta = quad * 4 + r, tb = 16 + quad * 4 + r;
        lit[ta * 776 + o]       = f2us(__logf(fmaxf(y0, EPS_)));
        lit[ta * 776 + 384 + o] = f2us(__logf(fmaxf(1.f - y0, EPS_)));
        lit[tb * 776 + o]       = f2us(__logf(fmaxf(y1, EPS_)));
        lit[tb * 776 + 384 + o] = f2us(__logf(fmaxf(1.f - y1, EPS_)));
      }
    }
  }
  __syncthreads();

  // ---- clause gemm: wave w -> clause tiles {2w,2w+1}; depth-4 B ring; 4 MFMA per iter pair ----
  {
    const int ct0 = wave * 2;
    const u16* bp0 = maskb + (size_t)((ct0 + 0) * 16 + l16) * NLIT + quad * 8;
    const u16* bp1 = maskb + (size_t)((ct0 + 1) * 16 + l16) * NLIT + quad * 8;
    short8 rb0[4], rb1[4];
    #pragma unroll
    for (int p = 0; p < 4; ++p) {
      rb0[p] = *reinterpret_cast<const short8*>(bp0 + p * 32);
      rb1[p] = *reinterpret_cast<const short8*>(bp1 + p * 32);
    }
    f32x4 c00 = {0.f, 0.f, 0.f, 0.f}, c01 = {0.f, 0.f, 0.f, 0.f};
    f32x4 c10 = {0.f, 0.f, 0.f, 0.f}, c11 = {0.f, 0.f, 0.f, 0.f};
    #pragma unroll
    for (int ks = 0; ks < 24; ++ks) {
      const int k0 = ks * 32 + quad * 8;
      short8 a0 = *reinterpret_cast<const short8*>(&lit[l16 * 776 + k0]);
      short8 a1 = *reinterpret_cast<const short8*>(&lit[(16 + l16) * 776 + k0]);
      short8 b0 = rb0[ks & 3], b1 = rb1[ks & 3];
      if (ks + 4 < 24) {
        rb0[ks & 3] = *reinterpret_cast<const short8*>(bp0 + (ks + 4) * 32);
        rb1[ks & 3] = *reinterpret_cast<const short8*>(bp1 + (ks + 4) * 32);
      }
      c00 = __builtin_amdgcn_mfma_f32_16x16x32_bf16(a0, b0, c00, 0, 0, 0);
      c10 = __builtin_amdgcn_mfma_f32_16x16x32_bf16(a1, b0, c10, 0, 0, 0);
      c01 = __builtin_amdgcn_mfma_f32_16x16x32_bf16(a0, b1, c01, 0, 0, 0);
      c11 = __builtin_amdgcn_mfma_f32_16x16x32_bf16(a1, b1, c11, 0, 0, 0);
    }
    #pragma unroll
    for (int r = 0; r < 4; ++r) {
      const int ta = quad * 4 + r, tb = 16 + quad * 4 + r;
      claT[ta * 136 + (ct0 + 0) * 16 + l16] = f2us(__expf(c00[r]));
      claT[ta * 136 + (ct0 + 1) * 16 + l16] = f2us(__expf(c01[r]));
      claT[tb * 136 + (ct0 + 0) * 16 + l16] = f2us(__expf(c10[r]));
      claT[tb * 136 + (ct0 + 1) * 16 + l16] = f2us(__expf(c11[r]));
    }
  }
  __syncthreads();

  // ---- logits = cla @ tm_out; 6 N-tiles over waves; fused blend epilogue (residual from LDS) ----
  for (int nt = wave; nt < 6; nt += 4) {
    f32x4 acc0 = {0.f, 0.f, 0.f, 0.f}, acc1 = {0.f, 0.f, 0.f, 0.f};
    #pragma unroll
    for (int ks = 0; ks < 4; ++ks) {
      const int k0 = ks * 32 + quad * 8;
      short8 a0 = *reinterpret_cast<const short8*>(&claT[l16 * 136 + k0]);
      short8 a1 = *reinterpret_cast<const short8*>(&claT[(16 + l16) * 136 + k0]);
      short8 b = *reinterpret_cast<const short8*>(
          tmoT + (size_t)(nt * 16 + l16) * NCL_ + k0);
      acc0 = __builtin_amdgcn_mfma_f32_16x16x32_bf16(a0, b, acc0, 0, 0, 0);
      acc1 = __builtin_amdgcn_mfma_f32_16x16x32_bf16(a1, b, acc1, 0, 0, 0);
    }
    const int c = nt * 16 + l16;
    #pragma unroll
    for (int r = 0; r < 4; ++r) {
      const int ta = quad * 4 + r, tb = 16 + quad * 4 + r;
      float lg0 = acc0[r], lg1 = acc1[r];
      out[(tok0 + ta) * NC + c] = sx1[ta * 100 + c] + gv * lg0 + (1.f - gv) * sigmoidf_(lg0);
      out[(tok0 + tb) * NC + c] = sx1[tb * 100 + c] + gv * lg1 + (1.f - gv) * sigmoidf_(lg1);
    }
  }
}

extern "C" void kernel_launch(void* const* d_in, const int* in_sizes, int n_in,
                              void* d_out, int out_size, void* d_ws, size_t ws_size,
                              hipStream_t stream) {
  (void)in_sizes; (void)n_in; (void)out_size; (void)ws_size;
  const float* x      = (const float*)d_in[0];
  const float* n1g    = (const float*)d_in[1];
  const float* n1b    = (const float*)d_in[2];
  const float* qkv_w  = (const float*)d_in[3];
  const float* qkv_b  = (const float*)d_in[4];
  const float* proj_w = (const float*)d_in[5];
  const float* proj_b = (const float*)d_in[6];
  const float* n2g    = (const float*)d_in[7];
  const float* n2b    = (const float*)d_in[8];
  const float* fng    = (const float*)d_in[9];
  const float* fnb    = (const float*)d_in[10];
  const float* pin_w  = (const float*)d_in[11];
  const float* pin_b  = (const float*)d_in[12];
  const float* tm_inc = (const float*)d_in[13];
  const float* tm_out = (const float*)d_in[14];
  const float* gate   = (const float*)d_in[15];

  float* x1 = (float*)d_ws;                         // NTOK*96 f32
  u16* maskb = (u16*)(x1 + (size_t)NTOK * NC);      // 128*768 bf16
  u16* pinwb = maskb + NCL_ * NLIT;                 // 384*96 bf16
  u16* tmoT  = pinwb + HID_ * NC;                   // 96*128 bf16
  u16* qkvwb = tmoT + NC * NCL_;                    // 288*96 bf16
  u16* projwb= qkvwb + 3 * NC * NC;                 // 96*96 bf16

  hipLaunchKernelGGL(k0_prep, dim3(384), dim3(256), 0, stream,
                     tm_inc, pin_w, tm_out, qkv_w, proj_w, maskb, pinwb, tmoT, qkvwb, projwb);
  hipLaunchKernelGGL(k2_attn, dim3(NWIN), dim3(256), 0, stream,
                     x, n1g, n1b, qkvwb, qkv_b, projwb, proj_b, x1);
  hipLaunchKernelGGL(k4_ffn, dim3(NTOK / 32), dim3(256), 0, stream,
                     x1, n2g, n2b, fng, fnb, pinwb, pin_b, maskb, tmoT, gate, (float*)d_out);
}

// Round 9
// 202.028 us; speedup vs baseline: 4.2855x; 1.0204x over previous
//
#include <hip/hip_runtime.h>

// ---- problem constants (B,H0,W0,C)=(16,56,56,96), NH=3, WS=7, SS=3, HID=384, NCL=128 ----
#define NB 16
#define NHH 56
#define NWW 56
#define NC 96
#define NL (NHH*NWW)          // 3136
#define NTOK (NB*NL)          // 50176
#define WSZ 7
#define NT 49                 // tokens per window
#define SSH 3
#define NWIN 1024             // 16 * 8 * 8
#define HDIM 32
#define HID_ 384
#define NCL_ 128
#define NLIT 768
#define EPS_ 1e-6f

typedef unsigned short u16;
typedef unsigned int   u32;
typedef __attribute__((ext_vector_type(8))) short short8;   // 8 bf16 (4 VGPRs)
typedef __attribute__((ext_vector_type(4))) float f32x4;    // MFMA C/D

__device__ __forceinline__ float us2f(u16 u) {
  union { u32 u; float f; } x; x.u = ((u32)u) << 16; return x.f;
}
__device__ __forceinline__ u16 f2us(float f) {   // RNE float->bf16
  union { float f; u32 u; } x; x.f = f;
  u32 lsb = (x.u >> 16) & 1u;
  return (u16)((x.u + 0x7fffu + lsb) >> 16);
}
__device__ __forceinline__ float sigmoidf_(float x) { return 1.f / (1.f + __expf(-x)); }

// ---------------- K0: build bf16 constants ----------------
__global__ __launch_bounds__(256) void k0_prep(const float* __restrict__ tm_inc,
                                               const float* __restrict__ pin_w,
                                               const float* __restrict__ tm_out,
                                               const float* __restrict__ qkv_w,
                                               const float* __restrict__ proj_w,
                                               u16* __restrict__ maskb,
                                               u16* __restrict__ pinwb,
                                               u16* __restrict__ tmoT,
                                               u16* __restrict__ qkvwb,
                                               u16* __restrict__ projwb) {
  int idx = blockIdx.x * 256 + threadIdx.x;
  if (idx < NCL_ * NLIT)
    maskb[idx] = (tm_inc[idx] > 0.f) ? (u16)0x3F80 : (u16)0;
  if (idx < HID_ * NC)
    pinwb[idx] = f2us(pin_w[idx]);
  if (idx < NC * NCL_) {
    int c = idx / NCL_, k = idx - c * NCL_;
    tmoT[idx] = f2us(tm_out[(size_t)k * NC + c]);
  }
  if (idx < 3 * NC * NC)
    qkvwb[idx] = f2us(qkv_w[idx]);
  if (idx < NC * NC)
    projwb[idx] = f2us(proj_w[idx]);
}

// ---------------- K2: LN1 + window gather + MFMA attention + proj + residual scatter ----------------
// One block = one window. 4 waves; wave w owns query rows 16w..16w+15. (unchanged from round 8)
__global__ __launch_bounds__(256) void k2_attn(const float* __restrict__ x,
                                               const float* __restrict__ n1g,
                                               const float* __restrict__ n1b,
                                               const u16* __restrict__ qkvwb,
                                               const float* __restrict__ qkv_b,
                                               const u16* __restrict__ projwb,
                                               const float* __restrict__ proj_b,
                                               float* __restrict__ x1) {
  __shared__ __align__(16) u16 syb[64 * 104];
  __shared__ __align__(16) u16 sq [64 * 104];
  __shared__ __align__(16) u16 sk [64 * 104];
  __shared__ __align__(16) u16 svT[96 * 72];
  __shared__ __align__(16) u16 sp [4 * 16 * 72];
  const int tid  = threadIdx.x;
  const int wave = tid >> 6;
  const int lane = tid & 63;
  const int l16  = lane & 15;
  const int quad = lane >> 4;
  const int win  = blockIdx.x;
  const int t0   = wave * 16;
  const int bb = win >> 6, wl = win & 63;
  const int hbase = (wl >> 3) * WSZ, wbase = (wl & 7) * WSZ;

  // ---- LN1 head: 4 threads per token; gather from x with inverse global roll ----
  {
    const int t = tid >> 2, s = tid & 3;
    if (t < NT) {
      int hp = hbase + t / WSZ, wp = wbase + t % WSZ;
      int h = hp + SSH; if (h >= NHH) h -= NHH;
      int w = wp + SSH; if (w >= NWW) w -= NWW;
      const float* xp = x + ((size_t)bb * NL + (size_t)h * NWW + w) * NC;
      float4 v[6];
      float sum = 0.f;
      #pragma unroll
      for (int k = 0; k < 6; ++k) {
        v[k] = *reinterpret_cast<const float4*>(xp + s * 4 + k * 16);
        sum += v[k].x + v[k].y + v[k].z + v[k].w;
      }
      sum += __shfl_xor(sum, 1); sum += __shfl_xor(sum, 2);
      float mean = sum * (1.f / 96.f);
      float ssq = 0.f;
      #pragma unroll
      for (int k = 0; k < 6; ++k) {
        float d0 = v[k].x - mean, d1 = v[k].y - mean;
        float d2 = v[k].z - mean, d3 = v[k].w - mean;
        ssq += d0 * d0 + d1 * d1 + d2 * d2 + d3 * d3;
      }
      ssq += __shfl_xor(ssq, 1); ssq += __shfl_xor(ssq, 2);
      float rstd = rsqrtf(ssq * (1.f / 96.f) + 1e-5f);
      #pragma unroll
      for (int k = 0; k < 6; ++k) {
        int c = s * 4 + k * 16;
        const float4 g4 = *reinterpret_cast<const float4*>(n1g + c);
        const float4 b4 = *reinterpret_cast<const float4*>(n1b + c);
        syb[t * 104 + c + 0] = f2us((v[k].x - mean) * rstd * g4.x + b4.x);
        syb[t * 104 + c + 1] = f2us((v[k].y - mean) * rstd * g4.y + b4.y);
        syb[t * 104 + c + 2] = f2us((v[k].z - mean) * rstd * g4.z + b4.z);
        syb[t * 104 + c + 3] = f2us((v[k].w - mean) * rstd * g4.w + b4.w);
      }
    } else {
      #pragma unroll
      for (int k = 0; k < 6; ++k) {
        int c = s * 4 + k * 16;
        syb[t * 104 + c + 0] = 0; syb[t * 104 + c + 1] = 0;
        syb[t * 104 + c + 2] = 0; syb[t * 104 + c + 3] = 0;
      }
    }
  }
  __syncthreads();

  // ---- QKV: M=64, N=288 (18 tiles), K=96 (3 steps); depth-4 B-frag ring ----
  {
    short8 afr[3];
    #pragma unroll
    for (int ks = 0; ks < 3; ++ks)
      afr[ks] = *reinterpret_cast<const short8*>(&syb[(t0 + l16) * 104 + quad * 8 + ks * 32]);
    short8 rb[4][3];
    #pragma unroll
    for (int p = 0; p < 4; ++p)
      #pragma unroll
      for (int ks = 0; ks < 3; ++ks)
        rb[p][ks] = *reinterpret_cast<const short8*>(
            qkvwb + (size_t)(p * 16 + l16) * NC + quad * 8 + ks * 32);
    #pragma unroll
    for (int nt = 0; nt < 18; ++nt) {
      const int n0 = nt * 16;
      const float bias = qkv_b[n0 + l16];
      short8 b0 = rb[nt & 3][0], b1 = rb[nt & 3][1], b2 = rb[nt & 3][2];
      if (nt + 4 < 18) {
        #pragma unroll
        for (int ks = 0; ks < 3; ++ks)
          rb[nt & 3][ks] = *reinterpret_cast<const short8*>(
              qkvwb + (size_t)((nt + 4) * 16 + l16) * NC + quad * 8 + ks * 32);
      }
      f32x4 acc = {0.f, 0.f, 0.f, 0.f};
      acc = __builtin_amdgcn_mfma_f32_16x16x32_bf16(afr[0], b0, acc, 0, 0, 0);
      acc = __builtin_amdgcn_mfma_f32_16x16x32_bf16(afr[1], b1, acc, 0, 0, 0);
      acc = __builtin_amdgcn_mfma_f32_16x16x32_bf16(afr[2], b2, acc, 0, 0, 0);
      const int part = nt / 6;                 // 0=q 1=k 2=v
      const int oc = n0 - part * 96 + l16;
      if (part < 2) {
        u16* dst = (part == 0) ? sq : sk;
        #pragma unroll
        for (int r = 0; r < 4; ++r)
          dst[(t0 + quad * 4 + r) * 104 + oc] = f2us(acc[r] + bias);
      } else {
        #pragma unroll
        for (int r = 0; r < 4; ++r)
          svT[oc * 72 + (t0 + quad * 4 + r)] = f2us(acc[r] + bias);
      }
    }
  }
  __syncthreads();

  // ---- per head: scores -> in-register softmax -> PV (all wave-private) ----
  u16* spw = sp + wave * 16 * 72;
  const float sscale = 0.17677669529663687f;
  for (int h = 0; h < 3; ++h) {
    const int d0 = h * HDIM;
    short8 qf = *reinterpret_cast<const short8*>(&sq[(t0 + l16) * 104 + d0 + quad * 8]);
    f32x4 s[4];
    #pragma unroll
    for (int nt = 0; nt < 4; ++nt) {
      short8 kf = *reinterpret_cast<const short8*>(&sk[(nt * 16 + l16) * 104 + d0 + quad * 8]);
      f32x4 a = {0.f, 0.f, 0.f, 0.f};
      s[nt] = __builtin_amdgcn_mfma_f32_16x16x32_bf16(qf, kf, a, 0, 0, 0);
    }
    #pragma unroll
    for (int nt = 0; nt < 4; ++nt)
      #pragma unroll
      for (int r = 0; r < 4; ++r) s[nt][r] *= sscale;
    if (l16 >= 1) {                       // key col 48+l16 >= 49 -> mask
      #pragma unroll
      for (int r = 0; r < 4; ++r) s[3][r] = -1e30f;
    }
    #pragma unroll
    for (int r = 0; r < 4; ++r) {
      float m = fmaxf(fmaxf(s[0][r], s[1][r]), fmaxf(s[2][r], s[3][r]));
      #pragma unroll
      for (int off = 8; off > 0; off >>= 1) m = fmaxf(m, __shfl_xor(m, off, 16));
      float e0 = __expf(s[0][r] - m), e1 = __expf(s[1][r] - m);
      float e2 = __expf(s[2][r] - m), e3 = __expf(s[3][r] - m);
      float sum = e0 + e1 + e2 + e3;
      #pragma unroll
      for (int off = 8; off > 0; off >>= 1) sum += __shfl_xor(sum, off, 16);
      float inv = 1.f / sum;
      const int row = quad * 4 + r;
      spw[row * 72 +      l16] = f2us(e0 * inv);
      spw[row * 72 + 16 + l16] = f2us(e1 * inv);
      spw[row * 72 + 32 + l16] = f2us(e2 * inv);
      spw[row * 72 + 48 + l16] = f2us(e3 * inv);
    }
    short8 pa[2];
    pa[0] = *reinterpret_cast<const short8*>(&spw[l16 * 72 + quad * 8]);
    pa[1] = *reinterpret_cast<const short8*>(&spw[l16 * 72 + 32 + quad * 8]);
    #pragma unroll
    for (int nt = 0; nt < 2; ++nt) {
      const int c0 = d0 + nt * 16;
      f32x4 acc = {0.f, 0.f, 0.f, 0.f};
      #pragma unroll
      for (int ks = 0; ks < 2; ++ks) {
        short8 vb = *reinterpret_cast<const short8*>(&svT[(c0 + l16) * 72 + ks * 32 + quad * 8]);
        acc = __builtin_amdgcn_mfma_f32_16x16x32_bf16(pa[ks], vb, acc, 0, 0, 0);
      }
      #pragma unroll
      for (int r = 0; r < 4; ++r)
        syb[(t0 + quad * 4 + r) * 104 + c0 + l16] = f2us(acc[r]);
    }
  }

  // ---- proj: N=96 (6 tiles), K=96 (3 steps); prefetched residuals + depth-2 B ring ----
  {
    short8 aa[3];
    #pragma unroll
    for (int ks = 0; ks < 3; ++ks)
      aa[ks] = *reinterpret_cast<const short8*>(&syb[(t0 + l16) * 104 + quad * 8 + ks * 32]);

    size_t tokr[4]; bool tval[4];
    #pragma unroll
    for (int r = 0; r < 4; ++r) {
      const int t = t0 + quad * 4 + r;
      tval[r] = (t < NT);
      int rr = t / WSZ + SSH; if (rr >= WSZ) rr -= WSZ;
      int qq = t % WSZ + SSH; if (qq >= WSZ) qq -= WSZ;
      tokr[r] = (size_t)bb * NL + (size_t)(hbase + rr) * NWW + (wbase + qq);
    }
    float xv[6][4];
    #pragma unroll
    for (int nt = 0; nt < 6; ++nt)
      #pragma unroll
      for (int r = 0; r < 4; ++r)
        xv[nt][r] = tval[r] ? x[tokr[r] * NC + nt * 16 + l16] : 0.f;

    short8 pbr[2][3];
    #pragma unroll
    for (int ks = 0; ks < 3; ++ks)
      pbr[0][ks] = *reinterpret_cast<const short8*>(
          projwb + (size_t)l16 * NC + quad * 8 + ks * 32);
    #pragma unroll
    for (int nt = 0; nt < 6; ++nt) {
      const int n0 = nt * 16;
      const float pb = proj_b[n0 + l16];
      short8 b0 = pbr[nt & 1][0], b1 = pbr[nt & 1][1], b2 = pbr[nt & 1][2];
      if (nt + 1 < 6) {
        #pragma unroll
        for (int ks = 0; ks < 3; ++ks)
          pbr[(nt + 1) & 1][ks] = *reinterpret_cast<const short8*>(
              projwb + (size_t)((nt + 1) * 16 + l16) * NC + quad * 8 + ks * 32);
      }
      f32x4 acc = {0.f, 0.f, 0.f, 0.f};
      acc = __builtin_amdgcn_mfma_f32_16x16x32_bf16(aa[0], b0, acc, 0, 0, 0);
      acc = __builtin_amdgcn_mfma_f32_16x16x32_bf16(aa[1], b1, acc, 0, 0, 0);
      acc = __builtin_amdgcn_mfma_f32_16x16x32_bf16(aa[2], b2, acc, 0, 0, 0);
      #pragma unroll
      for (int r = 0; r < 4; ++r) {
        if (tval[r])
          x1[tokr[r] * NC + n0 + l16] = xv[nt][r] + acc[r] + pb;
      }
    }
  }
}

// ---------------- K4: double-LN + TM-FFN via MFMA; 32 tokens/block, 8 waves (512 thr) ----------------
// LDS 77,824 B -> 2 blocks/CU -> 16 waves/CU (50% occupancy). Per-wave: pin 3 N-tiles,
// clause 1 tile, tm_out 6 tiles over waves 0-5.
__global__ __launch_bounds__(512) void k4_ffn(const float* __restrict__ x1,
                                              const float* __restrict__ g2,
                                              const float* __restrict__ b2,
                                              const float* __restrict__ gf,
                                              const float* __restrict__ bf,
                                              const u16* __restrict__ pinwb,
                                              const float* __restrict__ pin_b,
                                              const u16* __restrict__ maskb,
                                              const u16* __restrict__ tmoT,
                                              const float* __restrict__ gate,
                                              float* __restrict__ out) {
  __shared__ __align__(16) u16 szb[32 * 104];       // bf16 double-LN'd z
  __shared__ __align__(16) u16 lit[32 * 776];       // bf16 log-literals [t][j]
  __shared__ __align__(16) u16 claT[32 * 136];      // bf16 clauses [t][k]
  __shared__ __align__(16) float sx1[32 * 100];     // f32 x1 rows (epilogue residual)
  const int tid  = threadIdx.x;
  const int wave = tid >> 6;
  const int lane = tid & 63;
  const int l16  = lane & 15;
  const int quad = lane >> 4;
  const size_t tok0 = (size_t)blockIdx.x * 32;

  // ---- LN(LN(x1)) head: 16 lanes per token, 6 channels each (float2 x 3) ----
  {
    const int t = tid >> 4, s = tid & 15;
    const float* xp = x1 + (tok0 + t) * NC;
    float2 v[3];
    float sum = 0.f;
    #pragma unroll
    for (int k = 0; k < 3; ++k) {
      const int c = s * 2 + k * 32;
      v[k] = *reinterpret_cast<const float2*>(xp + c);
      sum += v[k].x + v[k].y;
      *reinterpret_cast<float2*>(&sx1[t * 100 + c]) = v[k];
    }
    #pragma unroll
    for (int off = 8; off > 0; off >>= 1) sum += __shfl_xor(sum, off, 16);
    const float mean = sum * (1.f / 96.f);
    float ssq = 0.f;
    #pragma unroll
    for (int k = 0; k < 3; ++k) {
      float d0 = v[k].x - mean, d1 = v[k].y - mean;
      ssq += d0 * d0 + d1 * d1;
    }
    #pragma unroll
    for (int off = 8; off > 0; off >>= 1) ssq += __shfl_xor(ssq, off, 16);
    const float rstd = rsqrtf(ssq * (1.f / 96.f) + 1e-5f);
    float tv[6];
    float sum2 = 0.f;
    #pragma unroll
    for (int k = 0; k < 3; ++k) {
      const int c = s * 2 + k * 32;
      const float2 gg = *reinterpret_cast<const float2*>(g2 + c);
      const float2 bb = *reinterpret_cast<const float2*>(b2 + c);
      tv[2 * k]     = (v[k].x - mean) * rstd * gg.x + bb.x;
      tv[2 * k + 1] = (v[k].y - mean) * rstd * gg.y + bb.y;
      sum2 += tv[2 * k] + tv[2 * k + 1];
    }
    #pragma unroll
    for (int off = 8; off > 0; off >>= 1) sum2 += __shfl_xor(sum2, off, 16);
    const float mean2 = sum2 * (1.f / 96.f);
    float ssq2 = 0.f;
    #pragma unroll
    for (int k = 0; k < 3; ++k) {
      float d0 = tv[2 * k] - mean2, d1 = tv[2 * k + 1] - mean2;
      ssq2 += d0 * d0 + d1 * d1;
    }
    #pragma unroll
    for (int off = 8; off > 0; off >>= 1) ssq2 += __shfl_xor(ssq2, off, 16);
    const float rstd2 = rsqrtf(ssq2 * (1.f / 96.f) + 1e-5f);
    #pragma unroll
    for (int k = 0; k < 3; ++k) {
      const int c = s * 2 + k * 32;
      const float2 gg = *reinterpret_cast<const float2*>(gf + c);
      const float2 bb = *reinterpret_cast<const float2*>(bf + c);
      u16 lo = f2us((tv[2 * k]     - mean2) * rstd2 * gg.x + bb.x);
      u16 hi = f2us((tv[2 * k + 1] - mean2) * rstd2 * gg.y + bb.y);
      *reinterpret_cast<u32*>(&szb[t * 104 + c]) = (u32)lo | ((u32)hi << 16);
    }
  }
  __syncthreads();

  const float gv = sigmoidf_(gate[0]);

  // A-frags for pin: 2 M-tiles x 3 k-steps
  short8 a_pin[2][3];
  #pragma unroll
  for (int mt = 0; mt < 2; ++mt)
    #pragma unroll
    for (int ks = 0; ks < 3; ++ks)
      a_pin[mt][ks] = *reinterpret_cast<const short8*>(
          &szb[(mt * 16 + l16) * 104 + quad * 8 + ks * 32]);

  // ---- pin gemm: wave w -> N-tiles [3w,3w+3); depth-2 B ring; 2 MFMA per B-frag ----
  {
    float pbias[3];
    #pragma unroll
    for (int i = 0; i < 3; ++i) pbias[i] = pin_b[(wave * 3 + i) * 16 + l16];
    short8 pb[2][3];
    #pragma unroll
    for (int ks = 0; ks < 3; ++ks)
      pb[0][ks] = *reinterpret_cast<const short8*>(
          pinwb + (size_t)(wave * 3 * 16 + l16) * NC + quad * 8 + ks * 32);
    #pragma unroll
    for (int i = 0; i < 3; ++i) {
      short8 b0 = pb[i & 1][0], b1 = pb[i & 1][1], b2 = pb[i & 1][2];
      if (i + 1 < 3) {
        const int n1 = (wave * 3 + i + 1) * 16;
        #pragma unroll
        for (int ks = 0; ks < 3; ++ks)
          pb[(i + 1) & 1][ks] = *reinterpret_cast<const short8*>(
              pinwb + (size_t)(n1 + l16) * NC + quad * 8 + ks * 32);
      }
      f32x4 acc0 = {0.f, 0.f, 0.f, 0.f}, acc1 = {0.f, 0.f, 0.f, 0.f};
      acc0 = __builtin_amdgcn_mfma_f32_16x16x32_bf16(a_pin[0][0], b0, acc0, 0, 0, 0);
      acc1 = __builtin_amdgcn_mfma_f32_16x16x32_bf16(a_pin[1][0], b0, acc1, 0, 0, 0);
      acc0 = __builtin_amdgcn_mfma_f32_16x16x32_bf16(a_pin[0][1], b1, acc0, 0, 0, 0);
      acc1 = __builtin_amdgcn_mfma_f32_16x16x32_bf16(a_pin[1][1], b1, acc1, 0, 0, 0);
      acc0 = __builtin_amdgcn_mfma_f32_16x16x32_bf16(a_pin[0][2], b2, acc0, 0, 0, 0);
      acc1 = __builtin_amdgcn_mfma_f32_16x16x32_bf16(a_pin[1][2], b2, acc1, 0, 0, 0);
      const int o = (wave * 3 + i) * 16 + l16;
      const float pbv = pbias[i];
      #pragma unroll
      for (int r = 0; r < 4; ++r) {
        float y0 = sigmoidf_(acc0[r] + pbv);
        float y1 = sigmoidf_(acc1[r] + pbv);
        const int ta = quad * 4 + r, tb = 16 + quad * 4 + r;
        lit[ta * 776 + o]       = f2us(__logf(fmaxf(y0, EPS_)));
        lit[ta * 776 + 384 + o] = f2us(__logf(fmaxf(1.f - y0, EPS_)));
        lit[tb * 776 + o]       = f2us(__logf(fmaxf(y1, EPS_)));
        lit[tb * 776 + 384 + o] = f2us(__logf(fmaxf(1.f - y1, EPS_)));
      }
    }
  }
  __syncthreads();

  // ---- clause gemm: wave w -> clause tile w; depth-4 B ring; 2 MFMA per B-frag ----
  {
    const int ct = wave;
    const u16* bp0 = maskb + (size_t)(ct * 16 + l16) * NLIT + quad * 8;
    short8 rb0[4];
    #pragma unroll
    for (int p = 0; p < 4; ++p)
      rb0[p] = *reinterpret_cast<const short8*>(bp0 + p * 32);
    f32x4 c00 = {0.f, 0.f, 0.f, 0.f}, c10 = {0.f, 0.f, 0.f, 0.f};
    #pragma unroll
    for (int ks = 0; ks < 24; ++ks) {
      const int k0 = ks * 32 + quad * 8;
      short8 a0 = *reinterpret_cast<const short8*>(&lit[l16 * 776 + k0]);
      short8 a1 = *reinterpret_cast<const short8*>(&lit[(16 + l16) * 776 + k0]);
      short8 b0 = rb0[ks & 3];
      if (ks + 4 < 24)
        rb0[ks & 3] = *reinterpret_cast<const short8*>(bp0 + (ks + 4) * 32);
      c00 = __builtin_amdgcn_mfma_f32_16x16x32_bf16(a0, b0, c00, 0, 0, 0);
      c10 = __builtin_amdgcn_mfma_f32_16x16x32_bf16(a1, b0, c10, 0, 0, 0);
    }
    #pragma unroll
    for (int r = 0; r < 4; ++r) {
      const int ta = quad * 4 + r, tb = 16 + quad * 4 + r;
      claT[ta * 136 + ct * 16 + l16] = f2us(__expf(c00[r]));
      claT[tb * 136 + ct * 16 + l16] = f2us(__expf(c10[r]));
    }
  }
  __syncthreads();

  // ---- logits = cla @ tm_out; 6 N-tiles over waves 0-5; fused blend epilogue ----
  if (wave < 6) {
    const int nt = wave;
    f32x4 acc0 = {0.f, 0.f, 0.f, 0.f}, acc1 = {0.f, 0.f, 0.f, 0.f};
    #pragma unroll
    for (int ks = 0; ks < 4; ++ks) {
      const int k0 = ks * 32 + quad * 8;
      short8 a0 = *reinterpret_cast<const short8*>(&claT[l16 * 136 + k0]);
      short8 a1 = *reinterpret_cast<const short8*>(&claT[(16 + l16) * 136 + k0]);
      short8 b = *reinterpret_cast<const short8*>(
          tmoT + (size_t)(nt * 16 + l16) * NCL_ + k0);
      acc0 = __builtin_amdgcn_mfma_f32_16x16x32_bf16(a0, b, acc0, 0, 0, 0);
      acc1 = __builtin_amdgcn_mfma_f32_16x16x32_bf16(a1, b, acc1, 0, 0, 0);
    }
    const int c = nt * 16 + l16;
    #pragma unroll
    for (int r = 0; r < 4; ++r) {
      const int ta = quad * 4 + r, tb = 16 + quad * 4 + r;
      float lg0 = acc0[r], lg1 = acc1[r];
      out[(tok0 + ta) * NC + c] = sx1[ta * 100 + c] + gv * lg0 + (1.f - gv) * sigmoidf_(lg0);
      out[(tok0 + tb) * NC + c] = sx1[tb * 100 + c] + gv * lg1 + (1.f - gv) * sigmoidf_(lg1);
    }
  }
}

extern "C" void kernel_launch(void* const* d_in, const int* in_sizes, int n_in,
                              void* d_out, int out_size, void* d_ws, size_t ws_size,
                              hipStream_t stream) {
  (void)in_sizes; (void)n_in; (void)out_size; (void)ws_size;
  const float* x      = (const float*)d_in[0];
  const float* n1g    = (const float*)d_in[1];
  const float* n1b    = (const float*)d_in[2];
  const float* qkv_w  = (const float*)d_in[3];
  const float* qkv_b  = (const float*)d_in[4];
  const float* proj_w = (const float*)d_in[5];
  const float* proj_b = (const float*)d_in[6];
  const float* n2g    = (const float*)d_in[7];
  const float* n2b    = (const float*)d_in[8];
  const float* fng    = (const float*)d_in[9];
  const float* fnb    = (const float*)d_in[10];
  const float* pin_w  = (const float*)d_in[11];
  const float* pin_b  = (const float*)d_in[12];
  const float* tm_inc = (const float*)d_in[13];
  const float* tm_out = (const float*)d_in[14];
  const float* gate   = (const float*)d_in[15];

  float* x1 = (float*)d_ws;                         // NTOK*96 f32
  u16* maskb = (u16*)(x1 + (size_t)NTOK * NC);      // 128*768 bf16
  u16* pinwb = maskb + NCL_ * NLIT;                 // 384*96 bf16
  u16* tmoT  = pinwb + HID_ * NC;                   // 96*128 bf16
  u16* qkvwb = tmoT + NC * NCL_;                    // 288*96 bf16
  u16* projwb= qkvwb + 3 * NC * NC;                 // 96*96 bf16

  hipLaunchKernelGGL(k0_prep, dim3(384), dim3(256), 0, stream,
                     tm_inc, pin_w, tm_out, qkv_w, proj_w, maskb, pinwb, tmoT, qkvwb, projwb);
  hipLaunchKernelGGL(k2_attn, dim3(NWIN), dim3(256), 0, stream,
                     x, n1g, n1b, qkvwb, qkv_b, projwb, proj_b, x1);
  hipLaunchKernelGGL(k4_ffn, dim3(NTOK / 32), dim3(512), 0, stream,
                     x1, n2g, n2b, fng, fnb, pinwb, pin_b, maskb, tmoT, gate, (float*)d_out);
}